// Round 5
// baseline (339.115 us; speedup 1.0000x reference)
//
#include <hip/hip_runtime.h>
#include <hip/hip_bf16.h>

#define IN_C 128
#define HID 64
#define HEADS 4
#define OUT_C 64
#define NEG_SLOPE 0.2f

typedef __attribute__((ext_vector_type(8))) short bfrag8;   // 8 bf16 (4 VGPR)
typedef __attribute__((ext_vector_type(4))) float facc4;    // mfma C/D

__device__ __forceinline__ float bf16u_to_f(unsigned short u) {
  return __uint_as_float(((unsigned)u) << 16);
}
__device__ __forceinline__ unsigned short f_to_bf16u(float f) {
  return __bfloat16_as_ushort(__float2bfloat16(f));
}

// ---------------------------------------------------------------------------
// x (fp32) -> bf16, 8 elems/thread.
// ---------------------------------------------------------------------------
__global__ __launch_bounds__(256) void cvt_bf16_kernel(
    const float* __restrict__ in, unsigned short* __restrict__ out, int n8) {
  int i = blockIdx.x * blockDim.x + threadIdx.x;
  if (i >= n8) return;
  float4 v0 = *reinterpret_cast<const float4*>(&in[(size_t)i * 8]);
  float4 v1 = *reinterpret_cast<const float4*>(&in[(size_t)i * 8 + 4]);
  unsigned short q[8];
  q[0] = f_to_bf16u(v0.x); q[1] = f_to_bf16u(v0.y);
  q[2] = f_to_bf16u(v0.z); q[3] = f_to_bf16u(v0.w);
  q[4] = f_to_bf16u(v1.x); q[5] = f_to_bf16u(v1.y);
  q[6] = f_to_bf16u(v1.z); q[7] = f_to_bf16u(v1.w);
  *reinterpret_cast<uint4*>(&out[(size_t)i * 8]) =
      *reinterpret_cast<const uint4*>(q);
}

// ---------------------------------------------------------------------------
// GEMM1 wide: 64x256 tile (full N in one block), K=128, 4 waves, MFMA
// 16x16x32. A bf16 [M,128]; B fp32 [128,256] converted in staging.
// Fused attention epilogue for 4 heads (head = fn>>2).
// ---------------------------------------------------------------------------
__global__ __launch_bounds__(256) void mfma_gemm1_wide(
    const unsigned short* __restrict__ A, const float* __restrict__ B,
    const float* __restrict__ att_src, const float* __restrict__ att_dst,
    unsigned short* __restrict__ Hout, float* __restrict__ a_src,
    float* __restrict__ a_dst, int M) {
  __shared__ unsigned short As[64 * 64];    // 8 KB, per k-tile
  __shared__ unsigned short Bs[256 * 64];   // 32 KB: [n][k-granules]
  const int t = threadIdx.x;
  const int wid = t >> 6, lane = t & 63;
  const int lg = lane >> 4, li = lane & 15;
  const int bm = blockIdx.x * 64;

  facc4 acc[16];
#pragma unroll
  for (int fn = 0; fn < 16; ++fn) acc[fn] = (facc4)(0.f);

#pragma unroll
  for (int kt = 0; kt < 2; ++kt) {
    // stage A: 2 passes x 256 thr x 16B over [64 rows][8 granules]
#pragma unroll
    for (int p = 0; p < 2; ++p) {
      int flat = t + p * 256;
      int row = flat >> 3, g = flat & 7;
      int gr = bm + row;
      uint4 v = make_uint4(0, 0, 0, 0);
      if (gr < M)
        v = *reinterpret_cast<const uint4*>(&A[(size_t)gr * 128 + kt * 64 + g * 8]);
      *reinterpret_cast<uint4*>(&As[row * 64 + ((g ^ (row & 7)) << 3)]) = v;
    }
    // stage B (fp32->bf16, transposed): 16 passes over [kg=16][n=256]
#pragma unroll
    for (int p = 0; p < 16; ++p) {
      int n = t;        // 0..255
      int kg = p;       // k-group of 4
      unsigned short q[4];
#pragma unroll
      for (int i = 0; i < 4; ++i)
        q[i] = f_to_bf16u(B[(size_t)(kt * 64 + kg * 4 + i) * 256 + n]);
      int g = kg >> 1, half = kg & 1;
      *reinterpret_cast<ushort4*>(&Bs[n * 64 + ((g ^ (n & 7)) << 3) + half * 4]) =
          *reinterpret_cast<const ushort4*>(q);
    }
    __syncthreads();
#pragma unroll
    for (int ks = 0; ks < 2; ++ks) {
      int arow = wid * 16 + li;
      int gk = ks * 4 + lg;
      bfrag8 a = *reinterpret_cast<const bfrag8*>(
          &As[arow * 64 + ((gk ^ (arow & 7)) << 3)]);
#pragma unroll
      for (int fn = 0; fn < 16; ++fn) {
        int col = fn * 16 + li;
        bfrag8 b = *reinterpret_cast<const bfrag8*>(
            &Bs[col * 64 + ((gk ^ (col & 7)) << 3)]);
        acc[fn] =
            __builtin_amdgcn_mfma_f32_16x16x32_bf16(a, b, acc[fn], 0, 0, 0);
      }
    }
    __syncthreads();
  }

  // Epilogue: bf16 H + per-head attention dots (head = fn>>2).
#pragma unroll
  for (int reg = 0; reg < 4; ++reg) {
    int row = bm + wid * 16 + lg * 4 + reg;
    if (row < M) {
#pragma unroll
      for (int fn = 0; fn < 16; ++fn)
        Hout[(size_t)row * 256 + fn * 16 + li] = f_to_bf16u(acc[fn][reg]);
    }
#pragma unroll
    for (int h = 0; h < 4; ++h) {
      float ps = 0.f, pd = 0.f;
#pragma unroll
      for (int q = 0; q < 4; ++q) {
        int fn = h * 4 + q;
        float c = acc[fn][reg];
        ps += c * att_src[fn * 16 + li];
        pd += c * att_dst[fn * 16 + li];
      }
#pragma unroll
      for (int m = 1; m < 16; m <<= 1) {
        ps += __shfl_xor(ps, m);
        pd += __shfl_xor(pd, m);
      }
      if (row < M && li == 0) {
        a_src[(size_t)row * 4 + h] = ps;
        a_dst[(size_t)row * 4 + h] = pd;
      }
    }
  }
}

// ---------------------------------------------------------------------------
// GEMM2: 64x64 tile MFMA + fused single-head attention epilogue (R3-verified).
// ---------------------------------------------------------------------------
__global__ __launch_bounds__(256) void mfma_gemm2(
    const unsigned short* __restrict__ A, const float* __restrict__ B,
    const float* __restrict__ att_src, const float* __restrict__ att_dst,
    unsigned short* __restrict__ Hout, float* __restrict__ a_src,
    float* __restrict__ a_dst, int M, int N, int K) {
  __shared__ unsigned short As[64 * 64];
  __shared__ unsigned short Bs[64 * 64];
  const int t = threadIdx.x;
  const int wid = t >> 6, lane = t & 63;
  const int lg = lane >> 4, li = lane & 15;
  const int bm = blockIdx.x * 64, bn = 0;

  facc4 acc[4];
#pragma unroll
  for (int fn = 0; fn < 4; ++fn) acc[fn] = (facc4)(0.f);

  const int ktiles = K >> 6;
  for (int kt = 0; kt < ktiles; ++kt) {
#pragma unroll
    for (int p = 0; p < 2; ++p) {
      int flat = t + p * 256;
      int row = flat >> 3, g = flat & 7;
      int gr = bm + row;
      uint4 v = make_uint4(0, 0, 0, 0);
      if (gr < M)
        v = *reinterpret_cast<const uint4*>(&A[(size_t)gr * K + kt * 64 + g * 8]);
      *reinterpret_cast<uint4*>(&As[row * 64 + ((g ^ (row & 7)) << 3)]) = v;
    }
#pragma unroll
    for (int p = 0; p < 4; ++p) {
      int flat = t + p * 256;
      int n = flat & 63, kg = flat >> 6;
      unsigned short q[4];
#pragma unroll
      for (int i = 0; i < 4; ++i)
        q[i] = f_to_bf16u(B[(size_t)(kt * 64 + kg * 4 + i) * N + bn + n]);
      int g = kg >> 1, half = kg & 1;
      *reinterpret_cast<ushort4*>(&Bs[n * 64 + ((g ^ (n & 7)) << 3) + half * 4]) =
          *reinterpret_cast<const ushort4*>(q);
    }
    __syncthreads();
#pragma unroll
    for (int ks = 0; ks < 2; ++ks) {
      int arow = wid * 16 + li;
      int gk = ks * 4 + lg;
      bfrag8 a = *reinterpret_cast<const bfrag8*>(
          &As[arow * 64 + ((gk ^ (arow & 7)) << 3)]);
#pragma unroll
      for (int fn = 0; fn < 4; ++fn) {
        int col = fn * 16 + li;
        bfrag8 b = *reinterpret_cast<const bfrag8*>(
            &Bs[col * 64 + ((gk ^ (col & 7)) << 3)]);
        acc[fn] =
            __builtin_amdgcn_mfma_f32_16x16x32_bf16(a, b, acc[fn], 0, 0, 0);
      }
    }
    __syncthreads();
  }

  float s_att[4], d_att[4];
#pragma unroll
  for (int fn = 0; fn < 4; ++fn) {
    s_att[fn] = att_src[fn * 16 + li];
    d_att[fn] = att_dst[fn * 16 + li];
  }
#pragma unroll
  for (int reg = 0; reg < 4; ++reg) {
    int row = bm + wid * 16 + lg * 4 + reg;
    float ps = 0.f, pd = 0.f;
#pragma unroll
    for (int fn = 0; fn < 4; ++fn) {
      float c = acc[fn][reg];
      ps += c * s_att[fn];
      pd += c * d_att[fn];
    }
#pragma unroll
    for (int m = 1; m < 16; m <<= 1) {
      ps += __shfl_xor(ps, m);
      pd += __shfl_xor(pd, m);
    }
    if (row < M) {
#pragma unroll
      for (int fn = 0; fn < 4; ++fn)
        Hout[(size_t)row * N + bn + fn * 16 + li] = f_to_bf16u(acc[fn][reg]);
      if (li == 0) {
        a_src[row] = ps;
        a_dst[row] = pd;
      }
    }
  }
}

// ---------------------------------------------------------------------------
// CSR build with 4-padded segments.
// ---------------------------------------------------------------------------
__global__ void hist_kernel(const int* __restrict__ dst, int E,
                            int* __restrict__ deg) {
  int e = blockIdx.x * blockDim.x + threadIdx.x;
  if (e < E) atomicAdd(&deg[dst[e]], 1);
}

__device__ __forceinline__ int pad4(int d) { return (d + 3) & ~3; }

__global__ __launch_bounds__(256) void scan_partial_kernel(
    const int* __restrict__ deg, int n, int* __restrict__ partials) {
  __shared__ int sm[256];
  int t = threadIdx.x;
  int i = blockIdx.x * 256 + t;
  sm[t] = (i < n) ? pad4(deg[i]) : 0;
  __syncthreads();
  for (int off = 128; off > 0; off >>= 1) {
    if (t < off) sm[t] += sm[t + off];
    __syncthreads();
  }
  if (t == 0) partials[blockIdx.x] = sm[0];
}

// Merged base-scan + expand: each block locally scans the (<=256) partials.
__global__ __launch_bounds__(256) void scan_expand_kernel(
    const int* __restrict__ deg, int n, const int* __restrict__ partials,
    int nb, int* __restrict__ offsets, int* __restrict__ cursor) {
  __shared__ int smp[256];
  __shared__ int sm[256];
  int t = threadIdx.x;
  smp[t] = (t < nb) ? partials[t] : 0;
  __syncthreads();
  for (int off = 1; off < 256; off <<= 1) {
    int u = (t >= off) ? smp[t - off] : 0;
    __syncthreads();
    smp[t] += u;
    __syncthreads();
  }
  int base = (blockIdx.x > 0) ? smp[blockIdx.x - 1] : 0;
  int i = blockIdx.x * 256 + t;
  int v = (i < n) ? pad4(deg[i]) : 0;
  sm[t] = v;
  __syncthreads();
  for (int off = 1; off < 256; off <<= 1) {
    int u = (t >= off) ? sm[t - off] : 0;
    __syncthreads();
    sm[t] += u;
    __syncthreads();
  }
  int excl = sm[t] - v + base;
  if (i < n) {
    offsets[i] = excl;
    cursor[i] = excl;
  }
}

__global__ void scatter_kernel(const int* __restrict__ src,
                               const int* __restrict__ dst, int E,
                               int* __restrict__ cursor,
                               int2* __restrict__ sedge) {
  int e = blockIdx.x * blockDim.x + threadIdx.x;
  if (e < E) {
    int d = dst[e];
    int pos = atomicAdd(&cursor[d], 1);
    sedge[pos] = make_int2(src[e], d);
  }
}

// ---------------------------------------------------------------------------
// Edge-parallel alpha precompute, layer 1 (4 heads). Pad slots -> p=0, src=0.
// ---------------------------------------------------------------------------
__global__ __launch_bounds__(256) void edge_p1_kernel(
    const int2* __restrict__ sedge, const float* __restrict__ as1,
    const float* __restrict__ ad1, float* __restrict__ p1,
    int* __restrict__ ssrc_c, int stride) {
  int i = blockIdx.x * blockDim.x + threadIdx.x;
  if (i >= stride) return;
  int2 e = sedge[i];
  bool valid = e.x >= 0;
  int s = valid ? e.x : 0;
  int d = valid ? e.y : 0;
  float4 a4 = *reinterpret_cast<const float4*>(&as1[s * 4]);
  float4 b4 = *reinterpret_cast<const float4*>(&ad1[d * 4]);
  float v[4] = {a4.x + b4.x, a4.y + b4.y, a4.z + b4.z, a4.w + b4.w};
#pragma unroll
  for (int h = 0; h < 4; ++h) {
    float x = v[h];
    x = (x > 0.f) ? x : NEG_SLOPE * x;
    float p = __expf(x);
    p1[(size_t)h * stride + i] = valid ? p : 0.f;
  }
  ssrc_c[i] = s;
}

// ---------------------------------------------------------------------------
// Layer-1 aggregation: one wave per dst node; gather-only; H queue 3 groups
// deep (12 gathers in flight), S/P queues in named registers.
// ---------------------------------------------------------------------------
__global__ __launch_bounds__(256) void agg1_kernel(
    const unsigned short* __restrict__ h1, const float* __restrict__ p1,
    const int* __restrict__ ssrc_c, const int* __restrict__ offsets,
    const int* __restrict__ deg, const float* __restrict__ bias,
    unsigned short* __restrict__ out, int n_nodes, int stride) {
  int wave = (int)((blockIdx.x * blockDim.x + threadIdx.x) >> 6);
  int lane = threadIdx.x & 63;
  if (wave >= n_nodes) return;
  int head = lane >> 4;
  int off = offsets[wave];
  int cnt = deg[wave];  // >= 1 (self-loop)
  int last = ((cnt + 3) >> 2) - 1;
  const int* S_ = ssrc_c + off;
  const float* P_ = p1 + (size_t)head * stride + off;

  auto ldS = [&](int g) {
    return *reinterpret_cast<const int4*>(S_ + min(g, last) * 4);
  };
  auto ldP = [&](int g) {
    return *reinterpret_cast<const float4*>(P_ + min(g, last) * 4);
  };
  auto gat = [&](int s) {
    return *reinterpret_cast<const ushort4*>(&h1[(size_t)s * 256 + lane * 4]);
  };

  int4 Sg;
  ushort4 H0, H1, H2, H3, H4, H5, H6, H7, H8, H9, H10, H11;
  Sg = ldS(0); H0 = gat(Sg.x); H1 = gat(Sg.y); H2 = gat(Sg.z); H3 = gat(Sg.w);
  Sg = ldS(1); H4 = gat(Sg.x); H5 = gat(Sg.y); H6 = gat(Sg.z); H7 = gat(Sg.w);
  Sg = ldS(2); H8 = gat(Sg.x); H9 = gat(Sg.y); H10 = gat(Sg.z); H11 = gat(Sg.w);
  int4 S3 = ldS(3);
  float4 P0 = ldP(0), P1v = ldP(1), P2v = ldP(2);

  float l = 0.f, a0 = 0.f, a1 = 0.f, a2 = 0.f, a3 = 0.f;
  for (int j = 0; j <= last; ++j) {
    int4 S4 = ldS(j + 4);
    float4 P3v = ldP(j + 3);
    l += P0.x + P0.y + P0.z + P0.w;
    a0 += P0.x * bf16u_to_f(H0.x) + P0.y * bf16u_to_f(H1.x) +
          P0.z * bf16u_to_f(H2.x) + P0.w * bf16u_to_f(H3.x);
    a1 += P0.x * bf16u_to_f(H0.y) + P0.y * bf16u_to_f(H1.y) +
          P0.z * bf16u_to_f(H2.y) + P0.w * bf16u_to_f(H3.y);
    a2 += P0.x * bf16u_to_f(H0.z) + P0.y * bf16u_to_f(H1.z) +
          P0.z * bf16u_to_f(H2.z) + P0.w * bf16u_to_f(H3.z);
    a3 += P0.x * bf16u_to_f(H0.w) + P0.y * bf16u_to_f(H1.w) +
          P0.z * bf16u_to_f(H2.w) + P0.w * bf16u_to_f(H3.w);
    H0 = H4; H1 = H5; H2 = H6; H3 = H7;
    H4 = H8; H5 = H9; H6 = H10; H7 = H11;
    H8 = gat(S3.x); H9 = gat(S3.y); H10 = gat(S3.z); H11 = gat(S3.w);
    S3 = S4;
    P0 = P1v; P1v = P2v; P2v = P3v;
  }
  float inv = 1.0f / l;
  int col = lane * 4;
  float4 b4 = *reinterpret_cast<const float4*>(&bias[col]);
  float o0 = a0 * inv + b4.x;
  float o1 = a1 * inv + b4.y;
  float o2 = a2 * inv + b4.z;
  float o3 = a3 * inv + b4.w;
  o0 = o0 > 0.f ? o0 : __expf(o0) - 1.f;
  o1 = o1 > 0.f ? o1 : __expf(o1) - 1.f;
  o2 = o2 > 0.f ? o2 : __expf(o2) - 1.f;
  o3 = o3 > 0.f ? o3 : __expf(o3) - 1.f;
  unsigned short q[4];
  q[0] = f_to_bf16u(o0); q[1] = f_to_bf16u(o1);
  q[2] = f_to_bf16u(o2); q[3] = f_to_bf16u(o3);
  *reinterpret_cast<ushort4*>(&out[(size_t)wave * 256 + col]) =
      *reinterpret_cast<const ushort4*>(q);
}

// ---------------------------------------------------------------------------
// Layer-2 aggregation with FUSED p computation (edge_p2 eliminated).
// Pipeline: S 3 ahead -> AS gather 2 ahead -> P compute 1 ahead -> consume.
// H queue 3 groups deep. Pads detected via raw sedge.x < 0.
// ---------------------------------------------------------------------------
__global__ __launch_bounds__(256) void agg2_kernel(
    const unsigned short* __restrict__ h2, const float* __restrict__ as2,
    const float* __restrict__ ad2, const int2* __restrict__ sedge,
    const int* __restrict__ offsets, const int* __restrict__ deg,
    const float* __restrict__ bias, float* __restrict__ out, int n_nodes) {
  int wave = (int)((blockIdx.x * blockDim.x + threadIdx.x) >> 6);
  int lane = threadIdx.x & 63;
  if (wave >= n_nodes) return;
  int off = offsets[wave];
  int cnt = deg[wave];
  int last = ((cnt + 3) >> 2) - 1;
  const int2* E_ = sedge + off;
  float ad = ad2[wave];

  auto ldS = [&](int g) {  // raw srcs (pads = -1)
    g = min(g, last);
    int4 a = *reinterpret_cast<const int4*>(E_ + g * 4);
    int4 b = *reinterpret_cast<const int4*>(E_ + g * 4 + 2);
    return make_int4(a.x, a.z, b.x, b.z);
  };
  auto gAS = [&](int4 s) {
    return make_float4(as2[max(s.x, 0)], as2[max(s.y, 0)], as2[max(s.z, 0)],
                       as2[max(s.w, 0)]);
  };
  auto mkP = [&](int4 s, float4 a) {
    float4 p;
    float e;
    e = a.x + ad; e = (e > 0.f) ? e : NEG_SLOPE * e;
    p.x = (s.x >= 0) ? __expf(e) : 0.f;
    e = a.y + ad; e = (e > 0.f) ? e : NEG_SLOPE * e;
    p.y = (s.y >= 0) ? __expf(e) : 0.f;
    e = a.z + ad; e = (e > 0.f) ? e : NEG_SLOPE * e;
    p.z = (s.z >= 0) ? __expf(e) : 0.f;
    e = a.w + ad; e = (e > 0.f) ? e : NEG_SLOPE * e;
    p.w = (s.w >= 0) ? __expf(e) : 0.f;
    return p;
  };
  auto gat = [&](int s) { return h2[(size_t)max(s, 0) * 64 + lane]; };

  int4 S0 = ldS(0), S1 = ldS(1), S2 = ldS(2), S3 = ldS(3);
  unsigned short H0 = gat(S0.x), H1 = gat(S0.y), H2 = gat(S0.z), H3 = gat(S0.w);
  unsigned short H4 = gat(S1.x), H5 = gat(S1.y), H6 = gat(S1.z), H7 = gat(S1.w);
  unsigned short H8 = gat(S2.x), H9 = gat(S2.y), H10 = gat(S2.z),
                 H11 = gat(S2.w);
  float4 AS1 = gAS(S1), AS2 = gAS(S2);
  float4 P0 = mkP(S0, gAS(S0)), P1v = mkP(S1, AS1);

  float l = 0.f, acc = 0.f;
  for (int j = 0; j <= last; ++j) {
    int4 S4 = ldS(j + 4);
    float4 AS3 = gAS(S3);
    float4 P2v = mkP(S2, AS2);
    l += P0.x + P0.y + P0.z + P0.w;
    acc += P0.x * bf16u_to_f(H0) + P0.y * bf16u_to_f(H1) +
           P0.z * bf16u_to_f(H2) + P0.w * bf16u_to_f(H3);
    H0 = H4; H1 = H5; H2 = H6; H3 = H7;
    H4 = H8; H5 = H9; H6 = H10; H7 = H11;
    H8 = gat(S3.x); H9 = gat(S3.y); H10 = gat(S3.z); H11 = gat(S3.w);
    S2 = S3; S3 = S4;
    AS2 = AS3;
    P0 = P1v; P1v = P2v;
  }
  out[(size_t)wave * 64 + lane] = acc / l + bias[lane];
}

// ---------------------------------------------------------------------------
extern "C" void kernel_launch(void* const* d_in, const int* in_sizes, int n_in,
                              void* d_out, int out_size, void* d_ws,
                              size_t ws_size, hipStream_t stream) {
  const float* x = (const float*)d_in[0];
  const int* edge_index = (const int*)d_in[1];
  const float* W1 = (const float*)d_in[2];
  const float* att_src1 = (const float*)d_in[3];
  const float* att_dst1 = (const float*)d_in[4];
  const float* b1 = (const float*)d_in[5];
  const float* W2 = (const float*)d_in[6];
  const float* att_src2 = (const float*)d_in[7];
  const float* att_dst2 = (const float*)d_in[8];
  const float* b2 = (const float*)d_in[9];

  const int n = in_sizes[0] / IN_C;  // 50000
  const int E = in_sizes[1] / 2;     // 850000
  const int* src = edge_index;
  const int* dst = edge_index + E;
  const int nb = (n + 255) / 256;
  const int stride = (E + 4 * n + 3) & ~3;  // padded-slot bound

  char* ws = (char*)d_ws;
  size_t off = 0;
  auto carve = [&](size_t bytes) -> void* {
    void* p = ws + off;
    off = (off + bytes + 255) & ~(size_t)255;
    return p;
  };
  unsigned short* xb = (unsigned short*)carve((size_t)n * IN_C * 2);
  unsigned short* h1b = (unsigned short*)carve((size_t)n * 256 * 2);
  unsigned short* hact = (unsigned short*)carve((size_t)n * 256 * 2);
  unsigned short* h2b = (unsigned short*)carve((size_t)n * 64 * 2);
  float* as1 = (float*)carve((size_t)n * 4 * 4);
  float* ad1 = (float*)carve((size_t)n * 4 * 4);
  float* as2 = (float*)carve((size_t)n * 4);
  float* ad2 = (float*)carve((size_t)n * 4);
  int* deg = (int*)carve((size_t)n * 4);
  int* offsets = (int*)carve((size_t)n * 4);
  int* cursor = (int*)carve((size_t)n * 4);
  int2* sedge = (int2*)carve((size_t)stride * 8);
  int* ssrc_c = (int*)carve((size_t)stride * 4);
  float* p1 = (float*)carve((size_t)stride * 4 * 4);
  int* partials = (int*)carve((size_t)nb * 4);

  hipMemsetAsync(deg, 0, (size_t)n * 4, stream);
  hipMemsetAsync(sedge, 0xFF, (size_t)stride * 8, stream);

  {
    int n8 = n * IN_C / 8;
    cvt_bf16_kernel<<<(n8 + 255) / 256, 256, 0, stream>>>(x, xb, n8);
  }
  // GEMM1 + attn1 fused (wide tile, A read once)
  mfma_gemm1_wide<<<(n + 63) / 64, 256, 0, stream>>>(
      xb, W1, att_src1, att_dst1, h1b, as1, ad1, n);
  // CSR build (padded)
  hist_kernel<<<(E + 255) / 256, 256, 0, stream>>>(dst, E, deg);
  scan_partial_kernel<<<nb, 256, 0, stream>>>(deg, n, partials);
  scan_expand_kernel<<<nb, 256, 0, stream>>>(deg, n, partials, nb, offsets,
                                             cursor);
  scatter_kernel<<<(E + 255) / 256, 256, 0, stream>>>(src, dst, E, cursor,
                                                      sedge);
  // alpha precompute layer 1, then gather-only aggregation
  edge_p1_kernel<<<(stride + 255) / 256, 256, 0, stream>>>(sedge, as1, ad1, p1,
                                                           ssrc_c, stride);
  agg1_kernel<<<(n * 64 + 255) / 256, 256, 0, stream>>>(
      h1b, p1, ssrc_c, offsets, deg, b1, hact, n, stride);
  // GEMM2 + attn2 fused
  mfma_gemm2<<<(n + 63) / 64, 256, 0, stream>>>(
      hact, W2, att_src2, att_dst2, h2b, as2, ad2, n, OUT_C, HEADS * HID);
  // aggregation layer 2 with fused p -> d_out
  agg2_kernel<<<(n * 64 + 255) / 256, 256, 0, stream>>>(
      h2b, as2, ad2, sedge, offsets, deg, b2, (float*)d_out, n);
}

// Round 6
// 329.605 us; speedup vs baseline: 1.0289x; 1.0289x over previous
//
#include <hip/hip_runtime.h>
#include <hip/hip_bf16.h>

#define IN_C 128
#define HID 64
#define HEADS 4
#define OUT_C 64
#define NEG_SLOPE 0.2f

typedef __attribute__((ext_vector_type(8))) short bfrag8;   // 8 bf16 (4 VGPR)
typedef __attribute__((ext_vector_type(4))) float facc4;    // mfma C/D

__device__ __forceinline__ float bf16u_to_f(unsigned short u) {
  return __uint_as_float(((unsigned)u) << 16);
}
__device__ __forceinline__ unsigned short f_to_bf16u(float f) {
  return __bfloat16_as_ushort(__float2bfloat16(f));
}
__device__ __forceinline__ float leaky(float x) {
  return (x > 0.f) ? x : NEG_SLOPE * x;
}

// ---------------------------------------------------------------------------
// W1/W2 fp32 -> bf16, pre-swizzled into the exact LDS tile image the GEMMs
// use: img[kt][n][64] with granule g at ((g ^ (n&7))<<3). One thread per
// 8-elem granule. W1: 2x256x8 = 4096 thr; W2: 4x64x8 = 2048 thr.
// ---------------------------------------------------------------------------
__global__ __launch_bounds__(256) void cvt_w_kernel(
    const float* __restrict__ W1, const float* __restrict__ W2,
    unsigned short* __restrict__ B1img, unsigned short* __restrict__ B2img) {
  int i = blockIdx.x * 256 + threadIdx.x;
  if (i < 4096) {
    int g = i & 7, n = (i >> 3) & 255, kt = i >> 11;
    unsigned short q[8];
#pragma unroll
    for (int e = 0; e < 8; ++e)
      q[e] = f_to_bf16u(W1[(size_t)(kt * 64 + g * 8 + e) * 256 + n]);
    *reinterpret_cast<uint4*>(&B1img[kt * 16384 + n * 64 + ((g ^ (n & 7)) << 3)]) =
        *reinterpret_cast<const uint4*>(q);
  } else if (i < 4096 + 2048) {
    int j = i - 4096;
    int g = j & 7, n = (j >> 3) & 63, kt = j >> 9;
    unsigned short q[8];
#pragma unroll
    for (int e = 0; e < 8; ++e)
      q[e] = f_to_bf16u(W2[(size_t)(kt * 64 + g * 8 + e) * 64 + n]);
    *reinterpret_cast<uint4*>(&B2img[kt * 4096 + n * 64 + ((g ^ (n & 7)) << 3)]) =
        *reinterpret_cast<const uint4*>(q);
  }
}

// ---------------------------------------------------------------------------
// GEMM1 wide: 64x256 tile (full N), K=128, 4 waves, MFMA 16x16x32.
// A: fp32 x, converted to bf16 during staging. B: preswizzled bf16 image
// (pure 16B copies). Fused 4-head attention epilogue.
// ---------------------------------------------------------------------------
__global__ __launch_bounds__(256) void mfma_gemm1_wide(
    const float* __restrict__ A, const unsigned short* __restrict__ B1img,
    const float* __restrict__ att_src, const float* __restrict__ att_dst,
    unsigned short* __restrict__ Hout, float* __restrict__ a_src,
    float* __restrict__ a_dst, int M) {
  __shared__ unsigned short As[64 * 64];    // 8 KB
  __shared__ unsigned short Bs[256 * 64];   // 32 KB
  const int t = threadIdx.x;
  const int wid = t >> 6, lane = t & 63;
  const int lg = lane >> 4, li = lane & 15;
  const int bm = blockIdx.x * 64;

  facc4 acc[16];
#pragma unroll
  for (int fn = 0; fn < 16; ++fn) acc[fn] = (facc4)(0.f);

#pragma unroll
  for (int kt = 0; kt < 2; ++kt) {
    // stage A: fp32 -> bf16 in-register; [64 rows][8 granules of 8]
#pragma unroll
    for (int p = 0; p < 2; ++p) {
      int flat = t + p * 256;
      int row = flat >> 3, g = flat & 7;
      int gr = bm + row;
      float4 v0 = make_float4(0.f, 0.f, 0.f, 0.f), v1 = v0;
      if (gr < M) {
        const float* src = &A[(size_t)gr * 128 + kt * 64 + g * 8];
        v0 = *reinterpret_cast<const float4*>(src);
        v1 = *reinterpret_cast<const float4*>(src + 4);
      }
      unsigned short q[8];
      q[0] = f_to_bf16u(v0.x); q[1] = f_to_bf16u(v0.y);
      q[2] = f_to_bf16u(v0.z); q[3] = f_to_bf16u(v0.w);
      q[4] = f_to_bf16u(v1.x); q[5] = f_to_bf16u(v1.y);
      q[6] = f_to_bf16u(v1.z); q[7] = f_to_bf16u(v1.w);
      *reinterpret_cast<uint4*>(&As[row * 64 + ((g ^ (row & 7)) << 3)]) =
          *reinterpret_cast<const uint4*>(q);
    }
    // stage B: pure 16B copies of the preswizzled image (L2-resident)
#pragma unroll
    for (int p = 0; p < 8; ++p) {
      int gi = t + p * 256;  // granule index 0..2047
      *reinterpret_cast<uint4*>(&Bs[gi * 8]) =
          *reinterpret_cast<const uint4*>(&B1img[kt * 16384 + gi * 8]);
    }
    __syncthreads();
#pragma unroll
    for (int ks = 0; ks < 2; ++ks) {
      int arow = wid * 16 + li;
      int gk = ks * 4 + lg;
      bfrag8 a = *reinterpret_cast<const bfrag8*>(
          &As[arow * 64 + ((gk ^ (arow & 7)) << 3)]);
#pragma unroll
      for (int fn = 0; fn < 16; ++fn) {
        int col = fn * 16 + li;
        bfrag8 b = *reinterpret_cast<const bfrag8*>(
            &Bs[col * 64 + ((gk ^ (col & 7)) << 3)]);
        acc[fn] =
            __builtin_amdgcn_mfma_f32_16x16x32_bf16(a, b, acc[fn], 0, 0, 0);
      }
    }
    __syncthreads();
  }

  // Epilogue: bf16 H + per-head attention dots (head = fn>>2).
#pragma unroll
  for (int reg = 0; reg < 4; ++reg) {
    int row = bm + wid * 16 + lg * 4 + reg;
    if (row < M) {
#pragma unroll
      for (int fn = 0; fn < 16; ++fn)
        Hout[(size_t)row * 256 + fn * 16 + li] = f_to_bf16u(acc[fn][reg]);
    }
#pragma unroll
    for (int h = 0; h < 4; ++h) {
      float ps = 0.f, pd = 0.f;
#pragma unroll
      for (int q = 0; q < 4; ++q) {
        int fn = h * 4 + q;
        float c = acc[fn][reg];
        ps += c * att_src[fn * 16 + li];
        pd += c * att_dst[fn * 16 + li];
      }
#pragma unroll
      for (int m = 1; m < 16; m <<= 1) {
        ps += __shfl_xor(ps, m);
        pd += __shfl_xor(pd, m);
      }
      if (row < M && li == 0) {
        a_src[(size_t)row * 4 + h] = ps;
        a_dst[(size_t)row * 4 + h] = pd;
      }
    }
  }
}

// ---------------------------------------------------------------------------
// GEMM2: 64x64 tile, K=256, bf16 A (hact), preswizzled B image. Fused
// single-head attention epilogue.
// ---------------------------------------------------------------------------
__global__ __launch_bounds__(256) void mfma_gemm2(
    const unsigned short* __restrict__ A, const unsigned short* __restrict__ B2img,
    const float* __restrict__ att_src, const float* __restrict__ att_dst,
    unsigned short* __restrict__ Hout, float* __restrict__ a_src,
    float* __restrict__ a_dst, int M) {
  __shared__ unsigned short As[64 * 64];
  __shared__ unsigned short Bs[64 * 64];
  const int t = threadIdx.x;
  const int wid = t >> 6, lane = t & 63;
  const int lg = lane >> 4, li = lane & 15;
  const int bm = blockIdx.x * 64;

  facc4 acc[4];
#pragma unroll
  for (int fn = 0; fn < 4; ++fn) acc[fn] = (facc4)(0.f);

#pragma unroll
  for (int kt = 0; kt < 4; ++kt) {
#pragma unroll
    for (int p = 0; p < 2; ++p) {
      int flat = t + p * 256;
      int row = flat >> 3, g = flat & 7;
      int gr = bm + row;
      uint4 v = make_uint4(0, 0, 0, 0);
      if (gr < M)
        v = *reinterpret_cast<const uint4*>(&A[(size_t)gr * 256 + kt * 64 + g * 8]);
      *reinterpret_cast<uint4*>(&As[row * 64 + ((g ^ (row & 7)) << 3)]) = v;
    }
#pragma unroll
    for (int p = 0; p < 2; ++p) {
      int gi = t + p * 256;  // 0..511
      *reinterpret_cast<uint4*>(&Bs[gi * 8]) =
          *reinterpret_cast<const uint4*>(&B2img[kt * 4096 + gi * 8]);
    }
    __syncthreads();
#pragma unroll
    for (int ks = 0; ks < 2; ++ks) {
      int arow = wid * 16 + li;
      int gk = ks * 4 + lg;
      bfrag8 a = *reinterpret_cast<const bfrag8*>(
          &As[arow * 64 + ((gk ^ (arow & 7)) << 3)]);
#pragma unroll
      for (int fn = 0; fn < 4; ++fn) {
        int col = fn * 16 + li;
        bfrag8 b = *reinterpret_cast<const bfrag8*>(
            &Bs[col * 64 + ((gk ^ (col & 7)) << 3)]);
        acc[fn] =
            __builtin_amdgcn_mfma_f32_16x16x32_bf16(a, b, acc[fn], 0, 0, 0);
      }
    }
    __syncthreads();
  }

  float s_att[4], d_att[4];
#pragma unroll
  for (int fn = 0; fn < 4; ++fn) {
    s_att[fn] = att_src[fn * 16 + li];
    d_att[fn] = att_dst[fn * 16 + li];
  }
#pragma unroll
  for (int reg = 0; reg < 4; ++reg) {
    int row = bm + wid * 16 + lg * 4 + reg;
    float ps = 0.f, pd = 0.f;
#pragma unroll
    for (int fn = 0; fn < 4; ++fn) {
      float c = acc[fn][reg];
      ps += c * s_att[fn];
      pd += c * d_att[fn];
    }
#pragma unroll
    for (int m = 1; m < 16; m <<= 1) {
      ps += __shfl_xor(ps, m);
      pd += __shfl_xor(pd, m);
    }
    if (row < M) {
#pragma unroll
      for (int fn = 0; fn < 4; ++fn)
        Hout[(size_t)row * 64 + fn * 16 + li] = f_to_bf16u(acc[fn][reg]);
      if (li == 0) {
        a_src[row] = ps;
        a_dst[row] = pd;
      }
    }
  }
}

// ---------------------------------------------------------------------------
// CSR build with 4-padded segments; compact src array only (pads = -1).
// ---------------------------------------------------------------------------
__global__ void hist_kernel(const int* __restrict__ dst, int E,
                            int* __restrict__ deg) {
  int e = blockIdx.x * blockDim.x + threadIdx.x;
  if (e < E) atomicAdd(&deg[dst[e]], 1);
}

__device__ __forceinline__ int pad4(int d) { return (d + 3) & ~3; }

__global__ __launch_bounds__(256) void scan_partial_kernel(
    const int* __restrict__ deg, int n, int* __restrict__ partials) {
  __shared__ int sm[256];
  int t = threadIdx.x;
  int i = blockIdx.x * 256 + t;
  sm[t] = (i < n) ? pad4(deg[i]) : 0;
  __syncthreads();
  for (int off = 128; off > 0; off >>= 1) {
    if (t < off) sm[t] += sm[t + off];
    __syncthreads();
  }
  if (t == 0) partials[blockIdx.x] = sm[0];
}

__global__ __launch_bounds__(256) void scan_expand_kernel(
    const int* __restrict__ deg, int n, const int* __restrict__ partials,
    int nb, int* __restrict__ offsets, int* __restrict__ cursor) {
  __shared__ int smp[256];
  __shared__ int sm[256];
  int t = threadIdx.x;
  smp[t] = (t < nb) ? partials[t] : 0;
  __syncthreads();
  for (int off = 1; off < 256; off <<= 1) {
    int u = (t >= off) ? smp[t - off] : 0;
    __syncthreads();
    smp[t] += u;
    __syncthreads();
  }
  int base = (blockIdx.x > 0) ? smp[blockIdx.x - 1] : 0;
  int i = blockIdx.x * 256 + t;
  int v = (i < n) ? pad4(deg[i]) : 0;
  sm[t] = v;
  __syncthreads();
  for (int off = 1; off < 256; off <<= 1) {
    int u = (t >= off) ? sm[t - off] : 0;
    __syncthreads();
    sm[t] += u;
    __syncthreads();
  }
  int excl = sm[t] - v + base;
  if (i < n) {
    offsets[i] = excl;
    cursor[i] = excl;
  }
}

__global__ void scatter_kernel(const int* __restrict__ src,
                               const int* __restrict__ dst, int E,
                               int* __restrict__ cursor,
                               int* __restrict__ ssrc) {
  int e = blockIdx.x * blockDim.x + threadIdx.x;
  if (e < E) {
    int d = dst[e];
    int pos = atomicAdd(&cursor[d], 1);
    ssrc[pos] = src[e];
  }
}

// ---------------------------------------------------------------------------
// Layer-1 aggregation, fused p: one wave per dst node; gather-only pipeline.
// S queue 3 ahead, AS gather 2 ahead, p compute 1 ahead, H 3 groups (12 rows)
// ahead. Lane l -> channels 4l..4l+3, head = l>>4. Pads: s = -1 -> p = 0.
// ---------------------------------------------------------------------------
__global__ __launch_bounds__(256) void agg1_kernel(
    const unsigned short* __restrict__ h1, const float* __restrict__ as1,
    const float* __restrict__ ad1, const int* __restrict__ ssrc,
    const int* __restrict__ offsets, const int* __restrict__ deg,
    const float* __restrict__ bias, unsigned short* __restrict__ out,
    int n_nodes) {
  int wave = (int)((blockIdx.x * blockDim.x + threadIdx.x) >> 6);
  int lane = threadIdx.x & 63;
  if (wave >= n_nodes) return;
  int head = lane >> 4;
  int off = offsets[wave];
  int cnt = deg[wave];  // >= 1 (self-loop)
  int last = ((cnt + 3) >> 2) - 1;
  const int* S_ = ssrc + off;
  float ad = ad1[wave * 4 + head];

  auto ldS = [&](int g) {
    return *reinterpret_cast<const int4*>(S_ + min(g, last) * 4);
  };
  auto gAS = [&](int4 s) {
    return make_float4(as1[max(s.x, 0) * 4 + head], as1[max(s.y, 0) * 4 + head],
                       as1[max(s.z, 0) * 4 + head], as1[max(s.w, 0) * 4 + head]);
  };
  auto mkP = [&](int4 s, float4 a) {
    float4 p;
    p.x = (s.x >= 0) ? __expf(leaky(a.x + ad)) : 0.f;
    p.y = (s.y >= 0) ? __expf(leaky(a.y + ad)) : 0.f;
    p.z = (s.z >= 0) ? __expf(leaky(a.z + ad)) : 0.f;
    p.w = (s.w >= 0) ? __expf(leaky(a.w + ad)) : 0.f;
    return p;
  };
  auto gat = [&](int s) {
    return *reinterpret_cast<const ushort4*>(
        &h1[(size_t)max(s, 0) * 256 + lane * 4]);
  };

  int4 S0 = ldS(0), S1 = ldS(1), S2 = ldS(2), S3 = ldS(3);
  ushort4 H0 = gat(S0.x), H1 = gat(S0.y), H2 = gat(S0.z), H3 = gat(S0.w);
  ushort4 H4 = gat(S1.x), H5 = gat(S1.y), H6 = gat(S1.z), H7 = gat(S1.w);
  ushort4 H8 = gat(S2.x), H9 = gat(S2.y), H10 = gat(S2.z), H11 = gat(S2.w);
  float4 AS2v = gAS(S2);
  float4 P0 = mkP(S0, gAS(S0)), P1v = mkP(S1, gAS(S1));

  float l = 0.f, a0 = 0.f, a1 = 0.f, a2 = 0.f, a3 = 0.f;
  for (int j = 0; j <= last; ++j) {
    int4 S4 = ldS(j + 4);
    float4 AS3v = gAS(S3);
    float4 P2v = mkP(S2, AS2v);
    l += P0.x + P0.y + P0.z + P0.w;
    a0 += P0.x * bf16u_to_f(H0.x) + P0.y * bf16u_to_f(H1.x) +
          P0.z * bf16u_to_f(H2.x) + P0.w * bf16u_to_f(H3.x);
    a1 += P0.x * bf16u_to_f(H0.y) + P0.y * bf16u_to_f(H1.y) +
          P0.z * bf16u_to_f(H2.y) + P0.w * bf16u_to_f(H3.y);
    a2 += P0.x * bf16u_to_f(H0.z) + P0.y * bf16u_to_f(H1.z) +
          P0.z * bf16u_to_f(H2.z) + P0.w * bf16u_to_f(H3.z);
    a3 += P0.x * bf16u_to_f(H0.w) + P0.y * bf16u_to_f(H1.w) +
          P0.z * bf16u_to_f(H2.w) + P0.w * bf16u_to_f(H3.w);
    H0 = H4; H1 = H5; H2 = H6; H3 = H7;
    H4 = H8; H5 = H9; H6 = H10; H7 = H11;
    H8 = gat(S3.x); H9 = gat(S3.y); H10 = gat(S3.z); H11 = gat(S3.w);
    S2 = S3; S3 = S4;
    AS2v = AS3v;
    P0 = P1v; P1v = P2v;
  }
  float inv = 1.0f / l;
  int col = lane * 4;
  float4 b4 = *reinterpret_cast<const float4*>(&bias[col]);
  float o0 = a0 * inv + b4.x;
  float o1 = a1 * inv + b4.y;
  float o2 = a2 * inv + b4.z;
  float o3 = a3 * inv + b4.w;
  o0 = o0 > 0.f ? o0 : __expf(o0) - 1.f;
  o1 = o1 > 0.f ? o1 : __expf(o1) - 1.f;
  o2 = o2 > 0.f ? o2 : __expf(o2) - 1.f;
  o3 = o3 > 0.f ? o3 : __expf(o3) - 1.f;
  unsigned short q[4];
  q[0] = f_to_bf16u(o0); q[1] = f_to_bf16u(o1);
  q[2] = f_to_bf16u(o2); q[3] = f_to_bf16u(o3);
  *reinterpret_cast<ushort4*>(&out[(size_t)wave * 256 + col]) =
      *reinterpret_cast<const ushort4*>(q);
}

// ---------------------------------------------------------------------------
// Layer-2 aggregation, fused p: same pipeline, lane = channel (2B gathers).
// ---------------------------------------------------------------------------
__global__ __launch_bounds__(256) void agg2_kernel(
    const unsigned short* __restrict__ h2, const float* __restrict__ as2,
    const float* __restrict__ ad2, const int* __restrict__ ssrc,
    const int* __restrict__ offsets, const int* __restrict__ deg,
    const float* __restrict__ bias, float* __restrict__ out, int n_nodes) {
  int wave = (int)((blockIdx.x * blockDim.x + threadIdx.x) >> 6);
  int lane = threadIdx.x & 63;
  if (wave >= n_nodes) return;
  int off = offsets[wave];
  int cnt = deg[wave];
  int last = ((cnt + 3) >> 2) - 1;
  const int* S_ = ssrc + off;
  float ad = ad2[wave];

  auto ldS = [&](int g) {
    return *reinterpret_cast<const int4*>(S_ + min(g, last) * 4);
  };
  auto gAS = [&](int4 s) {
    return make_float4(as2[max(s.x, 0)], as2[max(s.y, 0)], as2[max(s.z, 0)],
                       as2[max(s.w, 0)]);
  };
  auto mkP = [&](int4 s, float4 a) {
    float4 p;
    p.x = (s.x >= 0) ? __expf(leaky(a.x + ad)) : 0.f;
    p.y = (s.y >= 0) ? __expf(leaky(a.y + ad)) : 0.f;
    p.z = (s.z >= 0) ? __expf(leaky(a.z + ad)) : 0.f;
    p.w = (s.w >= 0) ? __expf(leaky(a.w + ad)) : 0.f;
    return p;
  };
  auto gat = [&](int s) { return h2[(size_t)max(s, 0) * 64 + lane]; };

  int4 S0 = ldS(0), S1 = ldS(1), S2 = ldS(2), S3 = ldS(3);
  unsigned short H0 = gat(S0.x), H1 = gat(S0.y), H2 = gat(S0.z), H3 = gat(S0.w);
  unsigned short H4 = gat(S1.x), H5 = gat(S1.y), H6 = gat(S1.z), H7 = gat(S1.w);
  unsigned short H8 = gat(S2.x), H9 = gat(S2.y), H10 = gat(S2.z),
                 H11 = gat(S2.w);
  float4 AS2v = gAS(S2);
  float4 P0 = mkP(S0, gAS(S0)), P1v = mkP(S1, gAS(S1));

  float l = 0.f, acc = 0.f;
  for (int j = 0; j <= last; ++j) {
    int4 S4 = ldS(j + 4);
    float4 AS3v = gAS(S3);
    float4 P2v = mkP(S2, AS2v);
    l += P0.x + P0.y + P0.z + P0.w;
    acc += P0.x * bf16u_to_f(H0) + P0.y * bf16u_to_f(H1) +
           P0.z * bf16u_to_f(H2) + P0.w * bf16u_to_f(H3);
    H0 = H4; H1 = H5; H2 = H6; H3 = H7;
    H4 = H8; H5 = H9; H6 = H10; H7 = H11;
    H8 = gat(S3.x); H9 = gat(S3.y); H10 = gat(S3.z); H11 = gat(S3.w);
    S2 = S3; S3 = S4;
    AS2v = AS3v;
    P0 = P1v; P1v = P2v;
  }
  out[(size_t)wave * 64 + lane] = acc / l + bias[lane];
}

// ---------------------------------------------------------------------------
extern "C" void kernel_launch(void* const* d_in, const int* in_sizes, int n_in,
                              void* d_out, int out_size, void* d_ws,
                              size_t ws_size, hipStream_t stream) {
  const float* x = (const float*)d_in[0];
  const int* edge_index = (const int*)d_in[1];
  const float* W1 = (const float*)d_in[2];
  const float* att_src1 = (const float*)d_in[3];
  const float* att_dst1 = (const float*)d_in[4];
  const float* b1 = (const float*)d_in[5];
  const float* W2 = (const float*)d_in[6];
  const float* att_src2 = (const float*)d_in[7];
  const float* att_dst2 = (const float*)d_in[8];
  const float* b2 = (const float*)d_in[9];

  const int n = in_sizes[0] / IN_C;  // 50000
  const int E = in_sizes[1] / 2;     // 850000
  const int* src = edge_index;
  const int* dst = edge_index + E;
  const int nb = (n + 255) / 256;
  const int stride = (E + 4 * n + 3) & ~3;  // padded-slot bound

  char* ws = (char*)d_ws;
  size_t off = 0;
  auto carve = [&](size_t bytes) -> void* {
    void* p = ws + off;
    off = (off + bytes + 255) & ~(size_t)255;
    return p;
  };
  unsigned short* h1b = (unsigned short*)carve((size_t)n * 256 * 2);
  unsigned short* hact = (unsigned short*)carve((size_t)n * 256 * 2);
  unsigned short* h2b = (unsigned short*)carve((size_t)n * 64 * 2);
  unsigned short* B1img = (unsigned short*)carve(32768 * 2);
  unsigned short* B2img = (unsigned short*)carve(16384 * 2);
  float* as1 = (float*)carve((size_t)n * 4 * 4);
  float* ad1 = (float*)carve((size_t)n * 4 * 4);
  float* as2 = (float*)carve((size_t)n * 4);
  float* ad2 = (float*)carve((size_t)n * 4);
  int* deg = (int*)carve((size_t)n * 4);
  int* offsets = (int*)carve((size_t)n * 4);
  int* cursor = (int*)carve((size_t)n * 4);
  int* ssrc = (int*)carve((size_t)stride * 4);
  int* partials = (int*)carve((size_t)nb * 4);

  hipMemsetAsync(deg, 0, (size_t)n * 4, stream);
  hipMemsetAsync(ssrc, 0xFF, (size_t)stride * 4, stream);  // pads = -1

  // W images (once per launch; tiny)
  cvt_w_kernel<<<24, 256, 0, stream>>>(W1, W2, B1img, B2img);
  // GEMM1 + attn1 fused (x converted in staging; B pure copy)
  mfma_gemm1_wide<<<(n + 63) / 64, 256, 0, stream>>>(
      x, B1img, att_src1, att_dst1, h1b, as1, ad1, n);
  // CSR build (padded)
  hist_kernel<<<(E + 255) / 256, 256, 0, stream>>>(dst, E, deg);
  scan_partial_kernel<<<nb, 256, 0, stream>>>(deg, n, partials);
  scan_expand_kernel<<<nb, 256, 0, stream>>>(deg, n, partials, nb, offsets,
                                             cursor);
  scatter_kernel<<<(E + 255) / 256, 256, 0, stream>>>(src, dst, E, cursor,
                                                      ssrc);
  // aggregation layer 1 (fused p, +bias+ELU) -> hact (bf16)
  agg1_kernel<<<(n * 64 + 255) / 256, 256, 0, stream>>>(
      h1b, as1, ad1, ssrc, offsets, deg, b1, hact, n);
  // GEMM2 + attn2 fused
  mfma_gemm2<<<(n + 63) / 64, 256, 0, stream>>>(hact, B2img, att_src2,
                                                att_dst2, h2b, as2, ad2, n);
  // aggregation layer 2 (fused p) -> d_out
  agg2_kernel<<<(n * 64 + 255) / 256, 256, 0, stream>>>(
      h2b, as2, ad2, ssrc, offsets, deg, b2, (float*)d_out, n);
}

// Round 7
// 312.815 us; speedup vs baseline: 1.0841x; 1.0537x over previous
//
#include <hip/hip_runtime.h>
#include <hip/hip_bf16.h>

#define IN_C 128
#define HID 64
#define HEADS 4
#define OUT_C 64
#define NEG_SLOPE 0.2f

typedef __attribute__((ext_vector_type(8))) short bfrag8;   // 8 bf16 (4 VGPR)
typedef __attribute__((ext_vector_type(4))) float facc4;    // mfma C/D

__device__ __forceinline__ float bf16u_to_f(unsigned short u) {
  return __uint_as_float(((unsigned)u) << 16);
}
__device__ __forceinline__ unsigned short f_to_bf16u(float f) {
  return __bfloat16_as_ushort(__float2bfloat16(f));
}
__device__ __forceinline__ float leaky(float x) {
  return (x > 0.f) ? x : NEG_SLOPE * x;
}

// ---------------------------------------------------------------------------
// W1/W2 fp32 -> bf16, pre-swizzled into the exact LDS tile image the GEMMs
// use (one thread per 8-elem granule).
// ---------------------------------------------------------------------------
__global__ __launch_bounds__(256) void cvt_w_kernel(
    const float* __restrict__ W1, const float* __restrict__ W2,
    unsigned short* __restrict__ B1img, unsigned short* __restrict__ B2img) {
  int i = blockIdx.x * 256 + threadIdx.x;
  if (i < 4096) {
    int g = i & 7, n = (i >> 3) & 255, kt = i >> 11;
    unsigned short q[8];
#pragma unroll
    for (int e = 0; e < 8; ++e)
      q[e] = f_to_bf16u(W1[(size_t)(kt * 64 + g * 8 + e) * 256 + n]);
    *reinterpret_cast<uint4*>(&B1img[kt * 16384 + n * 64 + ((g ^ (n & 7)) << 3)]) =
        *reinterpret_cast<const uint4*>(q);
  } else if (i < 4096 + 2048) {
    int j = i - 4096;
    int g = j & 7, n = (j >> 3) & 63, kt = j >> 9;
    unsigned short q[8];
#pragma unroll
    for (int e = 0; e < 8; ++e)
      q[e] = f_to_bf16u(W2[(size_t)(kt * 64 + g * 8 + e) * 64 + n]);
    *reinterpret_cast<uint4*>(&B2img[kt * 4096 + n * 64 + ((g ^ (n & 7)) << 3)]) =
        *reinterpret_cast<const uint4*>(q);
  }
}

// ---------------------------------------------------------------------------
// GEMM1 wide: 64x256 tile (full N), K=128, 4 waves, MFMA 16x16x32.
// ---------------------------------------------------------------------------
__global__ __launch_bounds__(256) void mfma_gemm1_wide(
    const float* __restrict__ A, const unsigned short* __restrict__ B1img,
    const float* __restrict__ att_src, const float* __restrict__ att_dst,
    unsigned short* __restrict__ Hout, float* __restrict__ a_src,
    float* __restrict__ a_dst, int M) {
  __shared__ unsigned short As[64 * 64];    // 8 KB
  __shared__ unsigned short Bs[256 * 64];   // 32 KB
  const int t = threadIdx.x;
  const int wid = t >> 6, lane = t & 63;
  const int lg = lane >> 4, li = lane & 15;
  const int bm = blockIdx.x * 64;

  facc4 acc[16];
#pragma unroll
  for (int fn = 0; fn < 16; ++fn) acc[fn] = (facc4)(0.f);

#pragma unroll
  for (int kt = 0; kt < 2; ++kt) {
#pragma unroll
    for (int p = 0; p < 2; ++p) {
      int flat = t + p * 256;
      int row = flat >> 3, g = flat & 7;
      int gr = bm + row;
      float4 v0 = make_float4(0.f, 0.f, 0.f, 0.f), v1 = v0;
      if (gr < M) {
        const float* src = &A[(size_t)gr * 128 + kt * 64 + g * 8];
        v0 = *reinterpret_cast<const float4*>(src);
        v1 = *reinterpret_cast<const float4*>(src + 4);
      }
      unsigned short q[8];
      q[0] = f_to_bf16u(v0.x); q[1] = f_to_bf16u(v0.y);
      q[2] = f_to_bf16u(v0.z); q[3] = f_to_bf16u(v0.w);
      q[4] = f_to_bf16u(v1.x); q[5] = f_to_bf16u(v1.y);
      q[6] = f_to_bf16u(v1.z); q[7] = f_to_bf16u(v1.w);
      *reinterpret_cast<uint4*>(&As[row * 64 + ((g ^ (row & 7)) << 3)]) =
          *reinterpret_cast<const uint4*>(q);
    }
#pragma unroll
    for (int p = 0; p < 8; ++p) {
      int gi = t + p * 256;
      *reinterpret_cast<uint4*>(&Bs[gi * 8]) =
          *reinterpret_cast<const uint4*>(&B1img[kt * 16384 + gi * 8]);
    }
    __syncthreads();
#pragma unroll
    for (int ks = 0; ks < 2; ++ks) {
      int arow = wid * 16 + li;
      int gk = ks * 4 + lg;
      bfrag8 a = *reinterpret_cast<const bfrag8*>(
          &As[arow * 64 + ((gk ^ (arow & 7)) << 3)]);
#pragma unroll
      for (int fn = 0; fn < 16; ++fn) {
        int col = fn * 16 + li;
        bfrag8 b = *reinterpret_cast<const bfrag8*>(
            &Bs[col * 64 + ((gk ^ (col & 7)) << 3)]);
        acc[fn] =
            __builtin_amdgcn_mfma_f32_16x16x32_bf16(a, b, acc[fn], 0, 0, 0);
      }
    }
    __syncthreads();
  }

#pragma unroll
  for (int reg = 0; reg < 4; ++reg) {
    int row = bm + wid * 16 + lg * 4 + reg;
    if (row < M) {
#pragma unroll
      for (int fn = 0; fn < 16; ++fn)
        Hout[(size_t)row * 256 + fn * 16 + li] = f_to_bf16u(acc[fn][reg]);
    }
#pragma unroll
    for (int h = 0; h < 4; ++h) {
      float ps = 0.f, pd = 0.f;
#pragma unroll
      for (int q = 0; q < 4; ++q) {
        int fn = h * 4 + q;
        float c = acc[fn][reg];
        ps += c * att_src[fn * 16 + li];
        pd += c * att_dst[fn * 16 + li];
      }
#pragma unroll
      for (int m = 1; m < 16; m <<= 1) {
        ps += __shfl_xor(ps, m);
        pd += __shfl_xor(pd, m);
      }
      if (row < M && li == 0) {
        a_src[(size_t)row * 4 + h] = ps;
        a_dst[(size_t)row * 4 + h] = pd;
      }
    }
  }
}

// ---------------------------------------------------------------------------
// GEMM2: 64x64 tile, K=256, bf16 A (hact), preswizzled B image.
// ---------------------------------------------------------------------------
__global__ __launch_bounds__(256) void mfma_gemm2(
    const unsigned short* __restrict__ A, const unsigned short* __restrict__ B2img,
    const float* __restrict__ att_src, const float* __restrict__ att_dst,
    unsigned short* __restrict__ Hout, float* __restrict__ a_src,
    float* __restrict__ a_dst, int M) {
  __shared__ unsigned short As[64 * 64];
  __shared__ unsigned short Bs[64 * 64];
  const int t = threadIdx.x;
  const int wid = t >> 6, lane = t & 63;
  const int lg = lane >> 4, li = lane & 15;
  const int bm = blockIdx.x * 64;

  facc4 acc[4];
#pragma unroll
  for (int fn = 0; fn < 4; ++fn) acc[fn] = (facc4)(0.f);

#pragma unroll
  for (int kt = 0; kt < 4; ++kt) {
#pragma unroll
    for (int p = 0; p < 2; ++p) {
      int flat = t + p * 256;
      int row = flat >> 3, g = flat & 7;
      int gr = bm + row;
      uint4 v = make_uint4(0, 0, 0, 0);
      if (gr < M)
        v = *reinterpret_cast<const uint4*>(&A[(size_t)gr * 256 + kt * 64 + g * 8]);
      *reinterpret_cast<uint4*>(&As[row * 64 + ((g ^ (row & 7)) << 3)]) = v;
    }
#pragma unroll
    for (int p = 0; p < 2; ++p) {
      int gi = t + p * 256;
      *reinterpret_cast<uint4*>(&Bs[gi * 8]) =
          *reinterpret_cast<const uint4*>(&B2img[kt * 4096 + gi * 8]);
    }
    __syncthreads();
#pragma unroll
    for (int ks = 0; ks < 2; ++ks) {
      int arow = wid * 16 + li;
      int gk = ks * 4 + lg;
      bfrag8 a = *reinterpret_cast<const bfrag8*>(
          &As[arow * 64 + ((gk ^ (arow & 7)) << 3)]);
#pragma unroll
      for (int fn = 0; fn < 4; ++fn) {
        int col = fn * 16 + li;
        bfrag8 b = *reinterpret_cast<const bfrag8*>(
            &Bs[col * 64 + ((gk ^ (col & 7)) << 3)]);
        acc[fn] =
            __builtin_amdgcn_mfma_f32_16x16x32_bf16(a, b, acc[fn], 0, 0, 0);
      }
    }
    __syncthreads();
  }

  float s_att[4], d_att[4];
#pragma unroll
  for (int fn = 0; fn < 4; ++fn) {
    s_att[fn] = att_src[fn * 16 + li];
    d_att[fn] = att_dst[fn * 16 + li];
  }
#pragma unroll
  for (int reg = 0; reg < 4; ++reg) {
    int row = bm + wid * 16 + lg * 4 + reg;
    float ps = 0.f, pd = 0.f;
#pragma unroll
    for (int fn = 0; fn < 4; ++fn) {
      float c = acc[fn][reg];
      ps += c * s_att[fn];
      pd += c * d_att[fn];
    }
#pragma unroll
    for (int m = 1; m < 16; m <<= 1) {
      ps += __shfl_xor(ps, m);
      pd += __shfl_xor(pd, m);
    }
    if (row < M) {
#pragma unroll
      for (int fn = 0; fn < 4; ++fn)
        Hout[(size_t)row * 64 + fn * 16 + li] = f_to_bf16u(acc[fn][reg]);
      if (li == 0) {
        a_src[row] = ps;
        a_dst[row] = pd;
      }
    }
  }
}

// ---------------------------------------------------------------------------
// CSR build with 4-padded segments; pads initialized to -1 by scan_expand.
// ---------------------------------------------------------------------------
__global__ void hist_kernel(const int* __restrict__ dst, int E,
                            int* __restrict__ deg) {
  int e = blockIdx.x * blockDim.x + threadIdx.x;
  if (e < E) atomicAdd(&deg[dst[e]], 1);
}

__device__ __forceinline__ int pad4(int d) { return (d + 3) & ~3; }

__global__ __launch_bounds__(256) void scan_partial_kernel(
    const int* __restrict__ deg, int n, int* __restrict__ partials) {
  __shared__ int sm[256];
  int t = threadIdx.x;
  int i = blockIdx.x * 256 + t;
  sm[t] = (i < n) ? pad4(deg[i]) : 0;
  __syncthreads();
  for (int off = 128; off > 0; off >>= 1) {
    if (t < off) sm[t] += sm[t + off];
    __syncthreads();
  }
  if (t == 0) partials[blockIdx.x] = sm[0];
}

__global__ __launch_bounds__(256) void scan_expand_kernel(
    const int* __restrict__ deg, int n, const int* __restrict__ partials,
    int nb, int* __restrict__ offsets, int* __restrict__ cursor,
    int* __restrict__ ssrc) {
  __shared__ int smp[256];
  __shared__ int sm[256];
  int t = threadIdx.x;
  smp[t] = (t < nb) ? partials[t] : 0;
  __syncthreads();
  for (int off = 1; off < 256; off <<= 1) {
    int u = (t >= off) ? smp[t - off] : 0;
    __syncthreads();
    smp[t] += u;
    __syncthreads();
  }
  int base = (blockIdx.x > 0) ? smp[blockIdx.x - 1] : 0;
  int i = blockIdx.x * 256 + t;
  int d = (i < n) ? deg[i] : 0;
  int v = pad4(d);
  sm[t] = v;
  __syncthreads();
  for (int off = 1; off < 256; off <<= 1) {
    int u = (t >= off) ? sm[t - off] : 0;
    __syncthreads();
    sm[t] += u;
    __syncthreads();
  }
  int excl = sm[t] - v + base;
  if (i < n) {
    offsets[i] = excl;
    cursor[i] = excl;
    for (int k = d; k < v; ++k) ssrc[excl + k] = -1;  // pad slots
  }
}

__global__ void scatter_kernel(const int* __restrict__ src,
                               const int* __restrict__ dst, int E,
                               int* __restrict__ cursor,
                               int* __restrict__ ssrc) {
  int e = blockIdx.x * blockDim.x + threadIdx.x;
  if (e < E) {
    int d = dst[e];
    int pos = atomicAdd(&cursor[d], 1);
    ssrc[pos] = src[e];
  }
}

// ---------------------------------------------------------------------------
// Layer-1 aggregation, lane-cooperative p: lane l computes p for edge (l&3)
// of head (l>>4) only (1 exp instead of 4), then 4x ds_bpermute broadcasts
// within the 16-lane head group. Gather-only deep pipeline otherwise.
// ---------------------------------------------------------------------------
__global__ __launch_bounds__(256) void agg1_kernel(
    const unsigned short* __restrict__ h1, const float* __restrict__ as1,
    const float* __restrict__ ad1, const int* __restrict__ ssrc,
    const int* __restrict__ offsets, const int* __restrict__ deg,
    const float* __restrict__ bias, unsigned short* __restrict__ out,
    int n_nodes) {
  int wave = (int)((blockIdx.x * blockDim.x + threadIdx.x) >> 6);
  int lane = threadIdx.x & 63;
  if (wave >= n_nodes) return;
  int head = lane >> 4;
  int off = offsets[wave];
  int cnt = deg[wave];  // >= 1 (self-loop)
  int last = ((cnt + 3) >> 2) - 1;
  const int* S_ = ssrc + off;
  float ad = ad1[wave * 4 + head];
  const int pbase = lane & 48;

  auto ldS = [&](int g) {
    return *reinterpret_cast<const int4*>(S_ + min(g, last) * 4);
  };
  // lane-cooperative: extract this lane's edge (k = lane&3), load its a_src
  auto gK = [&](int4 S, float* a_out) {
    int sk = (lane & 1) ? S.y : S.x;
    int sk2 = (lane & 1) ? S.w : S.z;
    sk = (lane & 2) ? sk2 : sk;
    *a_out = as1[max(sk, 0) * 4 + head];
    return sk;
  };
  auto mkP = [&](int sk, float a) {
    float pk = (sk >= 0) ? __expf(leaky(a + ad)) : 0.f;
    return make_float4(__shfl(pk, pbase), __shfl(pk, pbase + 1),
                       __shfl(pk, pbase + 2), __shfl(pk, pbase + 3));
  };
  auto gat = [&](int s) {
    return *reinterpret_cast<const ushort4*>(
        &h1[(size_t)max(s, 0) * 256 + lane * 4]);
  };

  int4 Sg0 = ldS(0), Sg1 = ldS(1), Sg2 = ldS(2), Sg3 = ldS(3);
  ushort4 H0 = gat(Sg0.x), H1 = gat(Sg0.y), H2 = gat(Sg0.z), H3 = gat(Sg0.w);
  ushort4 H4 = gat(Sg1.x), H5 = gat(Sg1.y), H6 = gat(Sg1.z), H7 = gat(Sg1.w);
  ushort4 H8 = gat(Sg2.x), H9 = gat(Sg2.y), H10 = gat(Sg2.z), H11 = gat(Sg2.w);
  float aK0, aK1, aK2;
  int sk0 = gK(Sg0, &aK0);
  int sk1 = gK(Sg1, &aK1);
  int sk2 = gK(Sg2, &aK2);
  float4 P0 = mkP(sk0, aK0), P1v = mkP(sk1, aK1);

  float l = 0.f, a0 = 0.f, a1 = 0.f, a2 = 0.f, a3 = 0.f;
  for (int j = 0; j <= last; ++j) {
    int4 Sg4 = ldS(j + 4);
    float aK3;
    int sk3 = gK(Sg3, &aK3);
    float4 P2v = mkP(sk2, aK2);
    l += P0.x + P0.y + P0.z + P0.w;
    a0 += P0.x * bf16u_to_f(H0.x) + P0.y * bf16u_to_f(H1.x) +
          P0.z * bf16u_to_f(H2.x) + P0.w * bf16u_to_f(H3.x);
    a1 += P0.x * bf16u_to_f(H0.y) + P0.y * bf16u_to_f(H1.y) +
          P0.z * bf16u_to_f(H2.y) + P0.w * bf16u_to_f(H3.y);
    a2 += P0.x * bf16u_to_f(H0.z) + P0.y * bf16u_to_f(H1.z) +
          P0.z * bf16u_to_f(H2.z) + P0.w * bf16u_to_f(H3.z);
    a3 += P0.x * bf16u_to_f(H0.w) + P0.y * bf16u_to_f(H1.w) +
          P0.z * bf16u_to_f(H2.w) + P0.w * bf16u_to_f(H3.w);
    H0 = H4; H1 = H5; H2 = H6; H3 = H7;
    H4 = H8; H5 = H9; H6 = H10; H7 = H11;
    H8 = gat(Sg3.x); H9 = gat(Sg3.y); H10 = gat(Sg3.z); H11 = gat(Sg3.w);
    Sg3 = Sg4;
    sk2 = sk3; aK2 = aK3;
    P0 = P1v; P1v = P2v;
  }
  float inv = 1.0f / l;
  int col = lane * 4;
  float4 b4 = *reinterpret_cast<const float4*>(&bias[col]);
  float o0 = a0 * inv + b4.x;
  float o1 = a1 * inv + b4.y;
  float o2 = a2 * inv + b4.z;
  float o3 = a3 * inv + b4.w;
  o0 = o0 > 0.f ? o0 : __expf(o0) - 1.f;
  o1 = o1 > 0.f ? o1 : __expf(o1) - 1.f;
  o2 = o2 > 0.f ? o2 : __expf(o2) - 1.f;
  o3 = o3 > 0.f ? o3 : __expf(o3) - 1.f;
  unsigned short q[4];
  q[0] = f_to_bf16u(o0); q[1] = f_to_bf16u(o1);
  q[2] = f_to_bf16u(o2); q[3] = f_to_bf16u(o3);
  *reinterpret_cast<ushort4*>(&out[(size_t)wave * 256 + col]) =
      *reinterpret_cast<const ushort4*>(q);
}

// ---------------------------------------------------------------------------
// Layer-2 aggregation, lane-cooperative p (broadcast from lanes 0-3).
// ---------------------------------------------------------------------------
__global__ __launch_bounds__(256) void agg2_kernel(
    const unsigned short* __restrict__ h2, const float* __restrict__ as2,
    const float* __restrict__ ad2, const int* __restrict__ ssrc,
    const int* __restrict__ offsets, const int* __restrict__ deg,
    const float* __restrict__ bias, float* __restrict__ out, int n_nodes) {
  int wave = (int)((blockIdx.x * blockDim.x + threadIdx.x) >> 6);
  int lane = threadIdx.x & 63;
  if (wave >= n_nodes) return;
  int off = offsets[wave];
  int cnt = deg[wave];
  int last = ((cnt + 3) >> 2) - 1;
  const int* S_ = ssrc + off;
  float ad = ad2[wave];

  auto ldS = [&](int g) {
    return *reinterpret_cast<const int4*>(S_ + min(g, last) * 4);
  };
  auto gK = [&](int4 S, float* a_out) {
    int sk = (lane & 1) ? S.y : S.x;
    int sk2 = (lane & 1) ? S.w : S.z;
    sk = (lane & 2) ? sk2 : sk;
    *a_out = as2[max(sk, 0)];
    return sk;
  };
  auto mkP = [&](int sk, float a) {
    float pk = (sk >= 0) ? __expf(leaky(a + ad)) : 0.f;
    return make_float4(__shfl(pk, 0), __shfl(pk, 1), __shfl(pk, 2),
                       __shfl(pk, 3));
  };
  auto gat = [&](int s) { return h2[(size_t)max(s, 0) * 64 + lane]; };

  int4 Sg0 = ldS(0), Sg1 = ldS(1), Sg2 = ldS(2), Sg3 = ldS(3);
  unsigned short H0 = gat(Sg0.x), H1 = gat(Sg0.y), H2 = gat(Sg0.z),
                 H3 = gat(Sg0.w);
  unsigned short H4 = gat(Sg1.x), H5 = gat(Sg1.y), H6 = gat(Sg1.z),
                 H7 = gat(Sg1.w);
  unsigned short H8 = gat(Sg2.x), H9 = gat(Sg2.y), H10 = gat(Sg2.z),
                 H11 = gat(Sg2.w);
  float aK0, aK1, aK2;
  int sk0 = gK(Sg0, &aK0);
  int sk1 = gK(Sg1, &aK1);
  int sk2 = gK(Sg2, &aK2);
  float4 P0 = mkP(sk0, aK0), P1v = mkP(sk1, aK1);

  float l = 0.f, acc = 0.f;
  for (int j = 0; j <= last; ++j) {
    int4 Sg4 = ldS(j + 4);
    float aK3;
    int sk3 = gK(Sg3, &aK3);
    float4 P2v = mkP(sk2, aK2);
    l += P0.x + P0.y + P0.z + P0.w;
    acc += P0.x * bf16u_to_f(H0) + P0.y * bf16u_to_f(H1) +
           P0.z * bf16u_to_f(H2) + P0.w * bf16u_to_f(H3);
    H0 = H4; H1 = H5; H2 = H6; H3 = H7;
    H4 = H8; H5 = H9; H6 = H10; H7 = H11;
    H8 = gat(Sg3.x); H9 = gat(Sg3.y); H10 = gat(Sg3.z); H11 = gat(Sg3.w);
    Sg3 = Sg4;
    sk2 = sk3; aK2 = aK3;
    P0 = P1v; P1v = P2v;
  }
  out[(size_t)wave * 64 + lane] = acc / l + bias[lane];
}

// ---------------------------------------------------------------------------
extern "C" void kernel_launch(void* const* d_in, const int* in_sizes, int n_in,
                              void* d_out, int out_size, void* d_ws,
                              size_t ws_size, hipStream_t stream) {
  const float* x = (const float*)d_in[0];
  const int* edge_index = (const int*)d_in[1];
  const float* W1 = (const float*)d_in[2];
  const float* att_src1 = (const float*)d_in[3];
  const float* att_dst1 = (const float*)d_in[4];
  const float* b1 = (const float*)d_in[5];
  const float* W2 = (const float*)d_in[6];
  const float* att_src2 = (const float*)d_in[7];
  const float* att_dst2 = (const float*)d_in[8];
  const float* b2 = (const float*)d_in[9];

  const int n = in_sizes[0] / IN_C;  // 50000
  const int E = in_sizes[1] / 2;     // 850000
  const int* src = edge_index;
  const int* dst = edge_index + E;
  const int nb = (n + 255) / 256;
  const int stride = (E + 4 * n + 3) & ~3;

  char* ws = (char*)d_ws;
  size_t off = 0;
  auto carve = [&](size_t bytes) -> void* {
    void* p = ws + off;
    off = (off + bytes + 255) & ~(size_t)255;
    return p;
  };
  unsigned short* h1b = (unsigned short*)carve((size_t)n * 256 * 2);
  unsigned short* hact = (unsigned short*)carve((size_t)n * 256 * 2);
  unsigned short* h2b = (unsigned short*)carve((size_t)n * 64 * 2);
  unsigned short* B1img = (unsigned short*)carve(32768 * 2);
  unsigned short* B2img = (unsigned short*)carve(16384 * 2);
  float* as1 = (float*)carve((size_t)n * 4 * 4);
  float* ad1 = (float*)carve((size_t)n * 4 * 4);
  float* as2 = (float*)carve((size_t)n * 4);
  float* ad2 = (float*)carve((size_t)n * 4);
  int* deg = (int*)carve((size_t)n * 4);
  int* offsets = (int*)carve((size_t)n * 4);
  int* cursor = (int*)carve((size_t)n * 4);
  int* ssrc = (int*)carve((size_t)stride * 4);
  int* partials = (int*)carve((size_t)nb * 4);

  hipMemsetAsync(deg, 0, (size_t)n * 4, stream);

  cvt_w_kernel<<<24, 256, 0, stream>>>(W1, W2, B1img, B2img);
  mfma_gemm1_wide<<<(n + 63) / 64, 256, 0, stream>>>(
      x, B1img, att_src1, att_dst1, h1b, as1, ad1, n);
  hist_kernel<<<(E + 255) / 256, 256, 0, stream>>>(dst, E, deg);
  scan_partial_kernel<<<nb, 256, 0, stream>>>(deg, n, partials);
  scan_expand_kernel<<<nb, 256, 0, stream>>>(deg, n, partials, nb, offsets,
                                             cursor, ssrc);
  scatter_kernel<<<(E + 255) / 256, 256, 0, stream>>>(src, dst, E, cursor,
                                                      ssrc);
  agg1_kernel<<<(n * 64 + 255) / 256, 256, 0, stream>>>(
      h1b, as1, ad1, ssrc, offsets, deg, b1, hact, n);
  mfma_gemm2<<<(n + 63) / 64, 256, 0, stream>>>(hact, B2img, att_src2,
                                                att_dst2, h2b, as2, ad2, n);
  agg2_kernel<<<(n * 64 + 255) / 256, 256, 0, stream>>>(
      h2b, as2, ad2, ssrc, offsets, deg, b2, (float*)d_out, n);
}

// Round 9
// 273.281 us; speedup vs baseline: 1.2409x; 1.1447x over previous
//
#include <hip/hip_runtime.h>
#include <hip/hip_bf16.h>

#define IN_C 128
#define HID 64
#define HEADS 4
#define OUT_C 64
#define NEG_SLOPE 0.2f

typedef __attribute__((ext_vector_type(8))) short bfrag8;   // 8 bf16 (4 VGPR)
typedef __attribute__((ext_vector_type(4))) float facc4;    // mfma C/D

__device__ __forceinline__ float bf16u_to_f(unsigned short u) {
  return __uint_as_float(((unsigned)u) << 16);
}
__device__ __forceinline__ float lof(unsigned u) {           // low bf16 of pair
  return __uint_as_float(u << 16);
}
__device__ __forceinline__ float hif(unsigned u) {           // high bf16 of pair
  return __uint_as_float(u & 0xffff0000u);
}
__device__ __forceinline__ unsigned short f_to_bf16u(float f) {
  return __bfloat16_as_ushort(__float2bfloat16(f));
}
__device__ __forceinline__ float leaky(float x) {
  return (x > 0.f) ? x : NEG_SLOPE * x;
}

// ---------------------------------------------------------------------------
// W1/W2 fp32 -> bf16, pre-swizzled into the exact LDS tile image the GEMMs
// use (one thread per 8-elem granule).
// ---------------------------------------------------------------------------
__global__ __launch_bounds__(256) void cvt_w_kernel(
    const float* __restrict__ W1, const float* __restrict__ W2,
    unsigned short* __restrict__ B1img, unsigned short* __restrict__ B2img) {
  int i = blockIdx.x * 256 + threadIdx.x;
  if (i < 4096) {
    int g = i & 7, n = (i >> 3) & 255, kt = i >> 11;
    unsigned short q[8];
#pragma unroll
    for (int e = 0; e < 8; ++e)
      q[e] = f_to_bf16u(W1[(size_t)(kt * 64 + g * 8 + e) * 256 + n]);
    *reinterpret_cast<uint4*>(&B1img[kt * 16384 + n * 64 + ((g ^ (n & 7)) << 3)]) =
        *reinterpret_cast<const uint4*>(q);
  } else if (i < 4096 + 2048) {
    int j = i - 4096;
    int g = j & 7, n = (j >> 3) & 63, kt = j >> 9;
    unsigned short q[8];
#pragma unroll
    for (int e = 0; e < 8; ++e)
      q[e] = f_to_bf16u(W2[(size_t)(kt * 64 + g * 8 + e) * 64 + n]);
    *reinterpret_cast<uint4*>(&B2img[kt * 4096 + n * 64 + ((g ^ (n & 7)) << 3)]) =
        *reinterpret_cast<const uint4*>(q);
  }
}

// ---------------------------------------------------------------------------
// GEMM1 wide: 64x256 tile (full N), K=128, 4 waves, MFMA 16x16x32.
// ---------------------------------------------------------------------------
__global__ __launch_bounds__(256) void mfma_gemm1_wide(
    const float* __restrict__ A, const unsigned short* __restrict__ B1img,
    const float* __restrict__ att_src, const float* __restrict__ att_dst,
    unsigned short* __restrict__ Hout, float* __restrict__ a_src,
    float* __restrict__ a_dst, int M) {
  __shared__ unsigned short As[64 * 64];    // 8 KB
  __shared__ unsigned short Bs[256 * 64];   // 32 KB
  const int t = threadIdx.x;
  const int wid = t >> 6, lane = t & 63;
  const int lg = lane >> 4, li = lane & 15;
  const int bm = blockIdx.x * 64;

  facc4 acc[16];
#pragma unroll
  for (int fn = 0; fn < 16; ++fn) acc[fn] = (facc4)(0.f);

#pragma unroll
  for (int kt = 0; kt < 2; ++kt) {
#pragma unroll
    for (int p = 0; p < 2; ++p) {
      int flat = t + p * 256;
      int row = flat >> 3, g = flat & 7;
      int gr = bm + row;
      float4 v0 = make_float4(0.f, 0.f, 0.f, 0.f), v1 = v0;
      if (gr < M) {
        const float* src = &A[(size_t)gr * 128 + kt * 64 + g * 8];
        v0 = *reinterpret_cast<const float4*>(src);
        v1 = *reinterpret_cast<const float4*>(src + 4);
      }
      unsigned short q[8];
      q[0] = f_to_bf16u(v0.x); q[1] = f_to_bf16u(v0.y);
      q[2] = f_to_bf16u(v0.z); q[3] = f_to_bf16u(v0.w);
      q[4] = f_to_bf16u(v1.x); q[5] = f_to_bf16u(v1.y);
      q[6] = f_to_bf16u(v1.z); q[7] = f_to_bf16u(v1.w);
      *reinterpret_cast<uint4*>(&As[row * 64 + ((g ^ (row & 7)) << 3)]) =
          *reinterpret_cast<const uint4*>(q);
    }
#pragma unroll
    for (int p = 0; p < 8; ++p) {
      int gi = t + p * 256;
      *reinterpret_cast<uint4*>(&Bs[gi * 8]) =
          *reinterpret_cast<const uint4*>(&B1img[kt * 16384 + gi * 8]);
    }
    __syncthreads();
#pragma unroll
    for (int ks = 0; ks < 2; ++ks) {
      int arow = wid * 16 + li;
      int gk = ks * 4 + lg;
      bfrag8 a = *reinterpret_cast<const bfrag8*>(
          &As[arow * 64 + ((gk ^ (arow & 7)) << 3)]);
#pragma unroll
      for (int fn = 0; fn < 16; ++fn) {
        int col = fn * 16 + li;
        bfrag8 b = *reinterpret_cast<const bfrag8*>(
            &Bs[col * 64 + ((gk ^ (col & 7)) << 3)]);
        acc[fn] =
            __builtin_amdgcn_mfma_f32_16x16x32_bf16(a, b, acc[fn], 0, 0, 0);
      }
    }
    __syncthreads();
  }

#pragma unroll
  for (int reg = 0; reg < 4; ++reg) {
    int row = bm + wid * 16 + lg * 4 + reg;
    if (row < M) {
#pragma unroll
      for (int fn = 0; fn < 16; ++fn)
        Hout[(size_t)row * 256 + fn * 16 + li] = f_to_bf16u(acc[fn][reg]);
    }
#pragma unroll
    for (int h = 0; h < 4; ++h) {
      float ps = 0.f, pd = 0.f;
#pragma unroll
      for (int q = 0; q < 4; ++q) {
        int fn = h * 4 + q;
        float c = acc[fn][reg];
        ps += c * att_src[fn * 16 + li];
        pd += c * att_dst[fn * 16 + li];
      }
#pragma unroll
      for (int m = 1; m < 16; m <<= 1) {
        ps += __shfl_xor(ps, m);
        pd += __shfl_xor(pd, m);
      }
      if (row < M && li == 0) {
        a_src[(size_t)row * 4 + h] = ps;
        a_dst[(size_t)row * 4 + h] = pd;
      }
    }
  }
}

// ---------------------------------------------------------------------------
// GEMM2: 64x64 tile, K=256, bf16 A (hact), preswizzled B image.
// ---------------------------------------------------------------------------
__global__ __launch_bounds__(256) void mfma_gemm2(
    const unsigned short* __restrict__ A, const unsigned short* __restrict__ B2img,
    const float* __restrict__ att_src, const float* __restrict__ att_dst,
    unsigned short* __restrict__ Hout, float* __restrict__ a_src,
    float* __restrict__ a_dst, int M) {
  __shared__ unsigned short As[64 * 64];
  __shared__ unsigned short Bs[64 * 64];
  const int t = threadIdx.x;
  const int wid = t >> 6, lane = t & 63;
  const int lg = lane >> 4, li = lane & 15;
  const int bm = blockIdx.x * 64;

  facc4 acc[4];
#pragma unroll
  for (int fn = 0; fn < 4; ++fn) acc[fn] = (facc4)(0.f);

#pragma unroll
  for (int kt = 0; kt < 4; ++kt) {
#pragma unroll
    for (int p = 0; p < 2; ++p) {
      int flat = t + p * 256;
      int row = flat >> 3, g = flat & 7;
      int gr = bm + row;
      uint4 v = make_uint4(0, 0, 0, 0);
      if (gr < M)
        v = *reinterpret_cast<const uint4*>(&A[(size_t)gr * 256 + kt * 64 + g * 8]);
      *reinterpret_cast<uint4*>(&As[row * 64 + ((g ^ (row & 7)) << 3)]) = v;
    }
#pragma unroll
    for (int p = 0; p < 2; ++p) {
      int gi = t + p * 256;
      *reinterpret_cast<uint4*>(&Bs[gi * 8]) =
          *reinterpret_cast<const uint4*>(&B2img[kt * 4096 + gi * 8]);
    }
    __syncthreads();
#pragma unroll
    for (int ks = 0; ks < 2; ++ks) {
      int arow = wid * 16 + li;
      int gk = ks * 4 + lg;
      bfrag8 a = *reinterpret_cast<const bfrag8*>(
          &As[arow * 64 + ((gk ^ (arow & 7)) << 3)]);
#pragma unroll
      for (int fn = 0; fn < 4; ++fn) {
        int col = fn * 16 + li;
        bfrag8 b = *reinterpret_cast<const bfrag8*>(
            &Bs[col * 64 + ((gk ^ (col & 7)) << 3)]);
        acc[fn] =
            __builtin_amdgcn_mfma_f32_16x16x32_bf16(a, b, acc[fn], 0, 0, 0);
      }
    }
    __syncthreads();
  }

  float s_att[4], d_att[4];
#pragma unroll
  for (int fn = 0; fn < 4; ++fn) {
    s_att[fn] = att_src[fn * 16 + li];
    d_att[fn] = att_dst[fn * 16 + li];
  }
#pragma unroll
  for (int reg = 0; reg < 4; ++reg) {
    int row = bm + wid * 16 + lg * 4 + reg;
    float ps = 0.f, pd = 0.f;
#pragma unroll
    for (int fn = 0; fn < 4; ++fn) {
      float c = acc[fn][reg];
      ps += c * s_att[fn];
      pd += c * d_att[fn];
    }
#pragma unroll
    for (int m = 1; m < 16; m <<= 1) {
      ps += __shfl_xor(ps, m);
      pd += __shfl_xor(pd, m);
    }
    if (row < M) {
#pragma unroll
      for (int fn = 0; fn < 4; ++fn)
        Hout[(size_t)row * 64 + fn * 16 + li] = f_to_bf16u(acc[fn][reg]);
      if (li == 0) {
        a_src[row] = ps;
        a_dst[row] = pd;
      }
    }
  }
}

// ---------------------------------------------------------------------------
// CSR build: hist records per-edge rank (atomic), scan pads to 4, scatter is
// atomic-free using offsets[dst]+rank.
// ---------------------------------------------------------------------------
__global__ void hist_rank_kernel(const int* __restrict__ dst, int E,
                                 int* __restrict__ deg, int* __restrict__ rank) {
  int e = blockIdx.x * blockDim.x + threadIdx.x;
  if (e < E) rank[e] = atomicAdd(&deg[dst[e]], 1);
}

__device__ __forceinline__ int pad4(int d) { return (d + 3) & ~3; }

__global__ __launch_bounds__(256) void scan_partial_kernel(
    const int* __restrict__ deg, int n, int* __restrict__ partials) {
  __shared__ int sm[256];
  int t = threadIdx.x;
  int i = blockIdx.x * 256 + t;
  sm[t] = (i < n) ? pad4(deg[i]) : 0;
  __syncthreads();
  for (int off = 128; off > 0; off >>= 1) {
    if (t < off) sm[t] += sm[t + off];
    __syncthreads();
  }
  if (t == 0) partials[blockIdx.x] = sm[0];
}

__global__ __launch_bounds__(256) void scan_expand_kernel(
    const int* __restrict__ deg, int n, const int* __restrict__ partials,
    int nb, int* __restrict__ offsets, int* __restrict__ ssrc) {
  __shared__ int smp[256];
  __shared__ int sm[256];
  int t = threadIdx.x;
  smp[t] = (t < nb) ? partials[t] : 0;
  __syncthreads();
  for (int off = 1; off < 256; off <<= 1) {
    int u = (t >= off) ? smp[t - off] : 0;
    __syncthreads();
    smp[t] += u;
    __syncthreads();
  }
  int base = (blockIdx.x > 0) ? smp[blockIdx.x - 1] : 0;
  int i = blockIdx.x * 256 + t;
  int d = (i < n) ? deg[i] : 0;
  int v = pad4(d);
  sm[t] = v;
  __syncthreads();
  for (int off = 1; off < 256; off <<= 1) {
    int u = (t >= off) ? sm[t - off] : 0;
    __syncthreads();
    sm[t] += u;
    __syncthreads();
  }
  int excl = sm[t] - v + base;
  if (i < n) {
    offsets[i] = excl;
    for (int k = d; k < v; ++k) ssrc[excl + k] = -1;  // pad slots
  }
}

__global__ void scatter_kernel(const int* __restrict__ src,
                               const int* __restrict__ dst,
                               const int* __restrict__ rank,
                               const int* __restrict__ offsets, int E,
                               int* __restrict__ ssrc) {
  int e = blockIdx.x * blockDim.x + threadIdx.x;
  if (e < E) ssrc[offsets[dst[e]] + rank[e]] = src[e];
}

// ---------------------------------------------------------------------------
// Layer-1 aggregation: 2-phase unrolled gather pipeline (register roles swap
// by NAME each phase -- zero queue movs). Lane-cooperative p (1 exp / group,
// broadcast via shfl in 16-lane head group). Lane l -> ch 4l..4l+3, head=l>>4.
// ---------------------------------------------------------------------------
__global__ __launch_bounds__(256) void agg1_kernel(
    const unsigned short* __restrict__ h1, const float* __restrict__ as1,
    const float* __restrict__ ad1, const int* __restrict__ ssrc,
    const int* __restrict__ offsets, const int* __restrict__ deg,
    const float* __restrict__ bias, unsigned short* __restrict__ out,
    int n_nodes) {
  int wave = (int)((blockIdx.x * blockDim.x + threadIdx.x) >> 6);
  int lane = threadIdx.x & 63;
  if (wave >= n_nodes) return;
  int head = lane >> 4;
  int off = offsets[wave];
  int cnt = deg[wave];  // >= 1 (self-loop)
  int last = ((cnt + 3) >> 2) - 1;
  const int* S_ = ssrc + off;
  float ad = ad1[wave * 4 + head];
  const int pbase = lane & 48;

  auto ldS = [&](int g) {
    return *reinterpret_cast<const int4*>(S_ + min(g, last) * 4);
  };
  auto gK = [&](int4 S, float* a_out) {
    int sk = (lane & 1) ? S.y : S.x;
    int sk2 = (lane & 1) ? S.w : S.z;
    sk = (lane & 2) ? sk2 : sk;
    *a_out = as1[max(sk, 0) * 4 + head];
    return sk;
  };
  auto mkP = [&](int sk, float a) {
    float pk = (sk >= 0) ? __expf(leaky(a + ad)) : 0.f;
    return make_float4(__shfl(pk, pbase), __shfl(pk, pbase + 1),
                       __shfl(pk, pbase + 2), __shfl(pk, pbase + 3));
  };
  auto gat = [&](int s) {
    return *reinterpret_cast<const uint2*>(
        &h1[(size_t)max(s, 0) * 256 + lane * 4]);
  };

  float l = 0.f, a0 = 0.f, a1 = 0.f, a2 = 0.f, a3 = 0.f;

  // Prologue: group0 (A), group1 (B), S(2) in SgP.
  int4 Sg0 = ldS(0), Sg1 = ldS(1);
  int4 SgP = ldS(2);
  uint2 HA0 = gat(Sg0.x), HA1 = gat(Sg0.y), HA2 = gat(Sg0.z), HA3 = gat(Sg0.w);
  uint2 HB0 = gat(Sg1.x), HB1 = gat(Sg1.y), HB2 = gat(Sg1.z), HB3 = gat(Sg1.w);
  float aKA, aKB;
  int skA = gK(Sg0, &aKA);
  int skB = gK(Sg1, &aKB);
  float4 PA = mkP(skA, aKA), PB;

  int j = 0;
  // One phase: consume (Pc, Hc*); produce p(j+1) into Pn from (skC,aKC);
  // issue group j+2 gathers into (Hc*, skN, aKN); advance SgP to S(j+3).
  auto step = [&](float4& Pc, float4& Pn, uint2& Hc0, uint2& Hc1, uint2& Hc2,
                  uint2& Hc3, int& skN, float& aKN, int skC, float aKC) {
    Pn = mkP(skC, aKC);
    skN = gK(SgP, &aKN);
    l += Pc.x + Pc.y + Pc.z + Pc.w;
    a0 += Pc.x * lof(Hc0.x) + Pc.y * lof(Hc1.x) + Pc.z * lof(Hc2.x) +
          Pc.w * lof(Hc3.x);
    a1 += Pc.x * hif(Hc0.x) + Pc.y * hif(Hc1.x) + Pc.z * hif(Hc2.x) +
          Pc.w * hif(Hc3.x);
    a2 += Pc.x * lof(Hc0.y) + Pc.y * lof(Hc1.y) + Pc.z * lof(Hc2.y) +
          Pc.w * lof(Hc3.y);
    a3 += Pc.x * hif(Hc0.y) + Pc.y * hif(Hc1.y) + Pc.z * hif(Hc2.y) +
          Pc.w * hif(Hc3.y);
    Hc0 = gat(SgP.x); Hc1 = gat(SgP.y); Hc2 = gat(SgP.z); Hc3 = gat(SgP.w);
    SgP = ldS(j + 3);
  };

  for (;;) {
    step(PA, PB, HA0, HA1, HA2, HA3, skA, aKA, skB, aKB);
    if (++j > last) break;
    step(PB, PA, HB0, HB1, HB2, HB3, skB, aKB, skA, aKA);
    if (++j > last) break;
  }

  float inv = 1.0f / l;
  int col = lane * 4;
  float4 b4 = *reinterpret_cast<const float4*>(&bias[col]);
  float o0 = a0 * inv + b4.x;
  float o1 = a1 * inv + b4.y;
  float o2 = a2 * inv + b4.z;
  float o3 = a3 * inv + b4.w;
  o0 = o0 > 0.f ? o0 : __expf(o0) - 1.f;
  o1 = o1 > 0.f ? o1 : __expf(o1) - 1.f;
  o2 = o2 > 0.f ? o2 : __expf(o2) - 1.f;
  o3 = o3 > 0.f ? o3 : __expf(o3) - 1.f;
  unsigned short q[4];
  q[0] = f_to_bf16u(o0); q[1] = f_to_bf16u(o1);
  q[2] = f_to_bf16u(o2); q[3] = f_to_bf16u(o3);
  *reinterpret_cast<ushort4*>(&out[(size_t)wave * 256 + col]) =
      *reinterpret_cast<const ushort4*>(q);
}

// ---------------------------------------------------------------------------
// Layer-2 aggregation: same 2-phase structure, lane = channel (2B gathers),
// p broadcast from lanes 0-3.
// ---------------------------------------------------------------------------
__global__ __launch_bounds__(256) void agg2_kernel(
    const unsigned short* __restrict__ h2, const float* __restrict__ as2,
    const float* __restrict__ ad2, const int* __restrict__ ssrc,
    const int* __restrict__ offsets, const int* __restrict__ deg,
    const float* __restrict__ bias, float* __restrict__ out, int n_nodes) {
  int wave = (int)((blockIdx.x * blockDim.x + threadIdx.x) >> 6);
  int lane = threadIdx.x & 63;
  if (wave >= n_nodes) return;
  int off = offsets[wave];
  int cnt = deg[wave];
  int last = ((cnt + 3) >> 2) - 1;
  const int* S_ = ssrc + off;
  float ad = ad2[wave];

  auto ldS = [&](int g) {
    return *reinterpret_cast<const int4*>(S_ + min(g, last) * 4);
  };
  auto gK = [&](int4 S, float* a_out) {
    int sk = (lane & 1) ? S.y : S.x;
    int sk2 = (lane & 1) ? S.w : S.z;
    sk = (lane & 2) ? sk2 : sk;
    *a_out = as2[max(sk, 0)];
    return sk;
  };
  auto mkP = [&](int sk, float a) {
    float pk = (sk >= 0) ? __expf(leaky(a + ad)) : 0.f;
    return make_float4(__shfl(pk, 0), __shfl(pk, 1), __shfl(pk, 2),
                       __shfl(pk, 3));
  };
  auto gat = [&](int s) { return h2[(size_t)max(s, 0) * 64 + lane]; };

  float l = 0.f, acc = 0.f;

  int4 Sg0 = ldS(0), Sg1 = ldS(1);
  int4 SgP = ldS(2);
  unsigned short HA0 = gat(Sg0.x), HA1 = gat(Sg0.y), HA2 = gat(Sg0.z),
                 HA3 = gat(Sg0.w);
  unsigned short HB0 = gat(Sg1.x), HB1 = gat(Sg1.y), HB2 = gat(Sg1.z),
                 HB3 = gat(Sg1.w);
  float aKA, aKB;
  int skA = gK(Sg0, &aKA);
  int skB = gK(Sg1, &aKB);
  float4 PA = mkP(skA, aKA), PB;

  int j = 0;
  auto step = [&](float4& Pc, float4& Pn, unsigned short& Hc0,
                  unsigned short& Hc1, unsigned short& Hc2, unsigned short& Hc3,
                  int& skN, float& aKN, int skC, float aKC) {
    Pn = mkP(skC, aKC);
    skN = gK(SgP, &aKN);
    l += Pc.x + Pc.y + Pc.z + Pc.w;
    acc += Pc.x * bf16u_to_f(Hc0) + Pc.y * bf16u_to_f(Hc1) +
           Pc.z * bf16u_to_f(Hc2) + Pc.w * bf16u_to_f(Hc3);
    Hc0 = gat(SgP.x); Hc1 = gat(SgP.y); Hc2 = gat(SgP.z); Hc3 = gat(SgP.w);
    SgP = ldS(j + 3);
  };

  for (;;) {
    step(PA, PB, HA0, HA1, HA2, HA3, skA, aKA, skB, aKB);
    if (++j > last) break;
    step(PB, PA, HB0, HB1, HB2, HB3, skB, aKB, skA, aKA);
    if (++j > last) break;
  }

  out[(size_t)wave * 64 + lane] = acc / l + bias[lane];
}

// ---------------------------------------------------------------------------
extern "C" void kernel_launch(void* const* d_in, const int* in_sizes, int n_in,
                              void* d_out, int out_size, void* d_ws,
                              size_t ws_size, hipStream_t stream) {
  const float* x = (const float*)d_in[0];
  const int* edge_index = (const int*)d_in[1];
  const float* W1 = (const float*)d_in[2];
  const float* att_src1 = (const float*)d_in[3];
  const float* att_dst1 = (const float*)d_in[4];
  const float* b1 = (const float*)d_in[5];
  const float* W2 = (const float*)d_in[6];
  const float* att_src2 = (const float*)d_in[7];
  const float* att_dst2 = (const float*)d_in[8];
  const float* b2 = (const float*)d_in[9];

  const int n = in_sizes[0] / IN_C;  // 50000
  const int E = in_sizes[1] / 2;     // 850000
  const int* src = edge_index;
  const int* dst = edge_index + E;
  const int nb = (n + 255) / 256;
  const int stride = (E + 4 * n + 3) & ~3;

  char* ws = (char*)d_ws;
  size_t off = 0;
  auto carve = [&](size_t bytes) -> void* {
    void* p = ws + off;
    off = (off + bytes + 255) & ~(size_t)255;
    return p;
  };
  unsigned short* h1b = (unsigned short*)carve((size_t)n * 256 * 2);
  unsigned short* hact = (unsigned short*)carve((size_t)n * 256 * 2);
  unsigned short* h2b = (unsigned short*)carve((size_t)n * 64 * 2);
  unsigned short* B1img = (unsigned short*)carve(32768 * 2);
  unsigned short* B2img = (unsigned short*)carve(16384 * 2);
  float* as1 = (float*)carve((size_t)n * 4 * 4);
  float* ad1 = (float*)carve((size_t)n * 4 * 4);
  float* as2 = (float*)carve((size_t)n * 4);
  float* ad2 = (float*)carve((size_t)n * 4);
  int* deg = (int*)carve((size_t)n * 4);
  int* offsets = (int*)carve((size_t)n * 4);
  int* rank = (int*)carve((size_t)E * 4);
  int* ssrc = (int*)carve((size_t)stride * 4);
  int* partials = (int*)carve((size_t)nb * 4);

  hipMemsetAsync(deg, 0, (size_t)n * 4, stream);

  cvt_w_kernel<<<24, 256, 0, stream>>>(W1, W2, B1img, B2img);
  mfma_gemm1_wide<<<(n + 63) / 64, 256, 0, stream>>>(
      x, B1img, att_src1, att_dst1, h1b, as1, ad1, n);
  hist_rank_kernel<<<(E + 255) / 256, 256, 0, stream>>>(dst, E, deg, rank);
  scan_partial_kernel<<<nb, 256, 0, stream>>>(deg, n, partials);
  scan_expand_kernel<<<nb, 256, 0, stream>>>(deg, n, partials, nb, offsets,
                                             ssrc);
  scatter_kernel<<<(E + 255) / 256, 256, 0, stream>>>(src, dst, rank, offsets,
                                                      E, ssrc);
  agg1_kernel<<<(n * 64 + 255) / 256, 256, 0, stream>>>(
      h1b, as1, ad1, ssrc, offsets, deg, b1, hact, n);
  mfma_gemm2<<<(n + 63) / 64, 256, 0, stream>>>(hact, B2img, att_src2,
                                                att_dst2, h2b, as2, ad2, n);
  agg2_kernel<<<(n * 64 + 255) / 256, 256, 0, stream>>>(
      h2b, as2, ad2, ssrc, offsets, deg, b2, (float*)d_out, n);
}

// Round 10
// 270.173 us; speedup vs baseline: 1.2552x; 1.0115x over previous
//
#include <hip/hip_runtime.h>
#include <hip/hip_bf16.h>

#define IN_C 128
#define HID 64
#define HEADS 4
#define OUT_C 64
#define NEG_SLOPE 0.2f

typedef __attribute__((ext_vector_type(8))) short bfrag8;   // 8 bf16 (4 VGPR)
typedef __attribute__((ext_vector_type(4))) float facc4;    // mfma C/D

__device__ __forceinline__ float bf16u_to_f(unsigned short u) {
  return __uint_as_float(((unsigned)u) << 16);
}
__device__ __forceinline__ float lof(unsigned u) {           // low bf16 of pair
  return __uint_as_float(u << 16);
}
__device__ __forceinline__ float hif(unsigned u) {           // high bf16 of pair
  return __uint_as_float(u & 0xffff0000u);
}
__device__ __forceinline__ unsigned short f_to_bf16u(float f) {
  return __bfloat16_as_ushort(__float2bfloat16(f));
}
__device__ __forceinline__ float leaky(float x) {
  return (x > 0.f) ? x : NEG_SLOPE * x;
}

// ---------------------------------------------------------------------------
// Setup: W1/W2 -> preswizzled bf16 LDS images (blocks 0..23) + deg zeroing
// (blocks 24..). One dispatch, no interdependence.
// ---------------------------------------------------------------------------
__global__ __launch_bounds__(256) void setup_kernel(
    const float* __restrict__ W1, const float* __restrict__ W2,
    unsigned short* __restrict__ B1img, unsigned short* __restrict__ B2img,
    int* __restrict__ deg, int n) {
  int bid = blockIdx.x;
  if (bid < 24) {
    int i = bid * 256 + threadIdx.x;
    if (i < 4096) {
      int g = i & 7, nn = (i >> 3) & 255, kt = i >> 11;
      unsigned short q[8];
#pragma unroll
      for (int e = 0; e < 8; ++e)
        q[e] = f_to_bf16u(W1[(size_t)(kt * 64 + g * 8 + e) * 256 + nn]);
      *reinterpret_cast<uint4*>(
          &B1img[kt * 16384 + nn * 64 + ((g ^ (nn & 7)) << 3)]) =
          *reinterpret_cast<const uint4*>(q);
    } else if (i < 4096 + 2048) {
      int j = i - 4096;
      int g = j & 7, nn = (j >> 3) & 63, kt = j >> 9;
      unsigned short q[8];
#pragma unroll
      for (int e = 0; e < 8; ++e)
        q[e] = f_to_bf16u(W2[(size_t)(kt * 64 + g * 8 + e) * 64 + nn]);
      *reinterpret_cast<uint4*>(
          &B2img[kt * 4096 + nn * 64 + ((g ^ (nn & 7)) << 3)]) =
          *reinterpret_cast<const uint4*>(q);
    }
  } else {
    int i = (bid - 24) * 1024 + threadIdx.x * 4;
    if (i < n)  // n % 4 == 0
      *reinterpret_cast<int4*>(&deg[i]) = make_int4(0, 0, 0, 0);
  }
}

// ---------------------------------------------------------------------------
// Fused GEMM1 (64x256 tile MFMA + attention epilogue) AND hist_rank
// (independent work; hist blocks fill CUs alongside gemm blocks).
// ---------------------------------------------------------------------------
__global__ __launch_bounds__(256) void gemm1_hist_kernel(
    const float* __restrict__ A, const unsigned short* __restrict__ B1img,
    const float* __restrict__ att_src, const float* __restrict__ att_dst,
    unsigned short* __restrict__ Hout, float* __restrict__ a_src,
    float* __restrict__ a_dst, int M, int G1,
    const int* __restrict__ dst, int E, int* __restrict__ deg,
    int* __restrict__ rank) {
  __shared__ unsigned short As[64 * 64];    // 8 KB
  __shared__ unsigned short Bs[256 * 64];   // 32 KB
  const int t = threadIdx.x;

  if ((int)blockIdx.x >= G1) {
    // ---- hist_rank: 4 edges/thread, vectorized loads ----
    int e0 = ((int)blockIdx.x - G1) * 1024 + t * 4;
    if (e0 + 3 < E) {
      int4 d4 = *reinterpret_cast<const int4*>(&dst[e0]);
      int4 r4;
      r4.x = atomicAdd(&deg[d4.x], 1);
      r4.y = atomicAdd(&deg[d4.y], 1);
      r4.z = atomicAdd(&deg[d4.z], 1);
      r4.w = atomicAdd(&deg[d4.w], 1);
      *reinterpret_cast<int4*>(&rank[e0]) = r4;
    } else {
      for (int e = e0; e < E; ++e) rank[e] = atomicAdd(&deg[dst[e]], 1);
    }
    return;
  }

  // ---- GEMM1 body ----
  const int wid = t >> 6, lane = t & 63;
  const int lg = lane >> 4, li = lane & 15;
  const int bm = blockIdx.x * 64;

  facc4 acc[16];
#pragma unroll
  for (int fn = 0; fn < 16; ++fn) acc[fn] = (facc4)(0.f);

#pragma unroll
  for (int kt = 0; kt < 2; ++kt) {
#pragma unroll
    for (int p = 0; p < 2; ++p) {
      int flat = t + p * 256;
      int row = flat >> 3, g = flat & 7;
      int gr = bm + row;
      float4 v0 = make_float4(0.f, 0.f, 0.f, 0.f), v1 = v0;
      if (gr < M) {
        const float* src = &A[(size_t)gr * 128 + kt * 64 + g * 8];
        v0 = *reinterpret_cast<const float4*>(src);
        v1 = *reinterpret_cast<const float4*>(src + 4);
      }
      unsigned short q[8];
      q[0] = f_to_bf16u(v0.x); q[1] = f_to_bf16u(v0.y);
      q[2] = f_to_bf16u(v0.z); q[3] = f_to_bf16u(v0.w);
      q[4] = f_to_bf16u(v1.x); q[5] = f_to_bf16u(v1.y);
      q[6] = f_to_bf16u(v1.z); q[7] = f_to_bf16u(v1.w);
      *reinterpret_cast<uint4*>(&As[row * 64 + ((g ^ (row & 7)) << 3)]) =
          *reinterpret_cast<const uint4*>(q);
    }
#pragma unroll
    for (int p = 0; p < 8; ++p) {
      int gi = t + p * 256;
      *reinterpret_cast<uint4*>(&Bs[gi * 8]) =
          *reinterpret_cast<const uint4*>(&B1img[kt * 16384 + gi * 8]);
    }
    __syncthreads();
#pragma unroll
    for (int ks = 0; ks < 2; ++ks) {
      int arow = wid * 16 + li;
      int gk = ks * 4 + lg;
      bfrag8 a = *reinterpret_cast<const bfrag8*>(
          &As[arow * 64 + ((gk ^ (arow & 7)) << 3)]);
#pragma unroll
      for (int fn = 0; fn < 16; ++fn) {
        int col = fn * 16 + li;
        bfrag8 b = *reinterpret_cast<const bfrag8*>(
            &Bs[col * 64 + ((gk ^ (col & 7)) << 3)]);
        acc[fn] =
            __builtin_amdgcn_mfma_f32_16x16x32_bf16(a, b, acc[fn], 0, 0, 0);
      }
    }
    __syncthreads();
  }

#pragma unroll
  for (int reg = 0; reg < 4; ++reg) {
    int row = bm + wid * 16 + lg * 4 + reg;
    if (row < M) {
#pragma unroll
      for (int fn = 0; fn < 16; ++fn)
        Hout[(size_t)row * 256 + fn * 16 + li] = f_to_bf16u(acc[fn][reg]);
    }
#pragma unroll
    for (int h = 0; h < 4; ++h) {
      float ps = 0.f, pd = 0.f;
#pragma unroll
      for (int q = 0; q < 4; ++q) {
        int fn = h * 4 + q;
        float c = acc[fn][reg];
        ps += c * att_src[fn * 16 + li];
        pd += c * att_dst[fn * 16 + li];
      }
#pragma unroll
      for (int m = 1; m < 16; m <<= 1) {
        ps += __shfl_xor(ps, m);
        pd += __shfl_xor(pd, m);
      }
      if (row < M && li == 0) {
        a_src[(size_t)row * 4 + h] = ps;
        a_dst[(size_t)row * 4 + h] = pd;
      }
    }
  }
}

// ---------------------------------------------------------------------------
// GEMM2: 64x64 tile, K=256, bf16 A (hact), preswizzled B image.
// ---------------------------------------------------------------------------
__global__ __launch_bounds__(256) void mfma_gemm2(
    const unsigned short* __restrict__ A, const unsigned short* __restrict__ B2img,
    const float* __restrict__ att_src, const float* __restrict__ att_dst,
    unsigned short* __restrict__ Hout, float* __restrict__ a_src,
    float* __restrict__ a_dst, int M) {
  __shared__ unsigned short As[64 * 64];
  __shared__ unsigned short Bs[64 * 64];
  const int t = threadIdx.x;
  const int wid = t >> 6, lane = t & 63;
  const int lg = lane >> 4, li = lane & 15;
  const int bm = blockIdx.x * 64;

  facc4 acc[4];
#pragma unroll
  for (int fn = 0; fn < 4; ++fn) acc[fn] = (facc4)(0.f);

#pragma unroll
  for (int kt = 0; kt < 4; ++kt) {
#pragma unroll
    for (int p = 0; p < 2; ++p) {
      int flat = t + p * 256;
      int row = flat >> 3, g = flat & 7;
      int gr = bm + row;
      uint4 v = make_uint4(0, 0, 0, 0);
      if (gr < M)
        v = *reinterpret_cast<const uint4*>(&A[(size_t)gr * 256 + kt * 64 + g * 8]);
      *reinterpret_cast<uint4*>(&As[row * 64 + ((g ^ (row & 7)) << 3)]) = v;
    }
#pragma unroll
    for (int p = 0; p < 2; ++p) {
      int gi = t + p * 256;
      *reinterpret_cast<uint4*>(&Bs[gi * 8]) =
          *reinterpret_cast<const uint4*>(&B2img[kt * 4096 + gi * 8]);
    }
    __syncthreads();
#pragma unroll
    for (int ks = 0; ks < 2; ++ks) {
      int arow = wid * 16 + li;
      int gk = ks * 4 + lg;
      bfrag8 a = *reinterpret_cast<const bfrag8*>(
          &As[arow * 64 + ((gk ^ (arow & 7)) << 3)]);
#pragma unroll
      for (int fn = 0; fn < 4; ++fn) {
        int col = fn * 16 + li;
        bfrag8 b = *reinterpret_cast<const bfrag8*>(
            &Bs[col * 64 + ((gk ^ (col & 7)) << 3)]);
        acc[fn] =
            __builtin_amdgcn_mfma_f32_16x16x32_bf16(a, b, acc[fn], 0, 0, 0);
      }
    }
    __syncthreads();
  }

  float s_att[4], d_att[4];
#pragma unroll
  for (int fn = 0; fn < 4; ++fn) {
    s_att[fn] = att_src[fn * 16 + li];
    d_att[fn] = att_dst[fn * 16 + li];
  }
#pragma unroll
  for (int reg = 0; reg < 4; ++reg) {
    int row = bm + wid * 16 + lg * 4 + reg;
    float ps = 0.f, pd = 0.f;
#pragma unroll
    for (int fn = 0; fn < 4; ++fn) {
      float c = acc[fn][reg];
      ps += c * s_att[fn];
      pd += c * d_att[fn];
    }
#pragma unroll
    for (int m = 1; m < 16; m <<= 1) {
      ps += __shfl_xor(ps, m);
      pd += __shfl_xor(pd, m);
    }
    if (row < M) {
#pragma unroll
      for (int fn = 0; fn < 4; ++fn)
        Hout[(size_t)row * 64 + fn * 16 + li] = f_to_bf16u(acc[fn][reg]);
      if (li == 0) {
        a_src[row] = ps;
        a_dst[row] = pd;
      }
    }
  }
}

// ---------------------------------------------------------------------------
// Scan (pad-4) and atomic-free scatter.
// ---------------------------------------------------------------------------
__device__ __forceinline__ int pad4(int d) { return (d + 3) & ~3; }

__global__ __launch_bounds__(256) void scan_partial_kernel(
    const int* __restrict__ deg, int n, int* __restrict__ partials) {
  __shared__ int sm[256];
  int t = threadIdx.x;
  int i = blockIdx.x * 256 + t;
  sm[t] = (i < n) ? pad4(deg[i]) : 0;
  __syncthreads();
  for (int off = 128; off > 0; off >>= 1) {
    if (t < off) sm[t] += sm[t + off];
    __syncthreads();
  }
  if (t == 0) partials[blockIdx.x] = sm[0];
}

__global__ __launch_bounds__(256) void scan_expand_kernel(
    const int* __restrict__ deg, int n, const int* __restrict__ partials,
    int nb, int* __restrict__ offsets, int* __restrict__ ssrc) {
  __shared__ int smp[256];
  __shared__ int sm[256];
  int t = threadIdx.x;
  smp[t] = (t < nb) ? partials[t] : 0;
  __syncthreads();
  for (int off = 1; off < 256; off <<= 1) {
    int u = (t >= off) ? smp[t - off] : 0;
    __syncthreads();
    smp[t] += u;
    __syncthreads();
  }
  int base = (blockIdx.x > 0) ? smp[blockIdx.x - 1] : 0;
  int i = blockIdx.x * 256 + t;
  int d = (i < n) ? deg[i] : 0;
  int v = pad4(d);
  sm[t] = v;
  __syncthreads();
  for (int off = 1; off < 256; off <<= 1) {
    int u = (t >= off) ? sm[t - off] : 0;
    __syncthreads();
    sm[t] += u;
    __syncthreads();
  }
  int excl = sm[t] - v + base;
  if (i < n) {
    offsets[i] = excl;
    for (int k = d; k < v; ++k) ssrc[excl + k] = -1;  // pad slots
  }
}

__global__ void scatter_kernel(const int* __restrict__ src,
                               const int* __restrict__ dst,
                               const int* __restrict__ rank,
                               const int* __restrict__ offsets, int E,
                               int* __restrict__ ssrc) {
  int e0 = (blockIdx.x * blockDim.x + threadIdx.x) * 4;
  if (e0 + 3 < E) {
    int4 s4 = *reinterpret_cast<const int4*>(&src[e0]);
    int4 d4 = *reinterpret_cast<const int4*>(&dst[e0]);
    int4 r4 = *reinterpret_cast<const int4*>(&rank[e0]);
    ssrc[offsets[d4.x] + r4.x] = s4.x;
    ssrc[offsets[d4.y] + r4.y] = s4.y;
    ssrc[offsets[d4.z] + r4.z] = s4.z;
    ssrc[offsets[d4.w] + r4.w] = s4.w;
  } else {
    for (int e = e0; e < E; ++e) ssrc[offsets[dst[e]] + rank[e]] = src[e];
  }
}

// ---------------------------------------------------------------------------
// Layer-1 aggregation: 2-phase unrolled gather pipeline (zero queue movs),
// lane-cooperative p (1 exp / group, shfl broadcast in 16-lane head group).
// ---------------------------------------------------------------------------
__global__ __launch_bounds__(256) void agg1_kernel(
    const unsigned short* __restrict__ h1, const float* __restrict__ as1,
    const float* __restrict__ ad1, const int* __restrict__ ssrc,
    const int* __restrict__ offsets, const int* __restrict__ deg,
    const float* __restrict__ bias, unsigned short* __restrict__ out,
    int n_nodes) {
  int wave = (int)((blockIdx.x * blockDim.x + threadIdx.x) >> 6);
  int lane = threadIdx.x & 63;
  if (wave >= n_nodes) return;
  int head = lane >> 4;
  int off = offsets[wave];
  int cnt = deg[wave];  // >= 1 (self-loop)
  int last = ((cnt + 3) >> 2) - 1;
  const int* S_ = ssrc + off;
  float ad = ad1[wave * 4 + head];
  const int pbase = lane & 48;

  auto ldS = [&](int g) {
    return *reinterpret_cast<const int4*>(S_ + min(g, last) * 4);
  };
  auto gK = [&](int4 S, float* a_out) {
    int sk = (lane & 1) ? S.y : S.x;
    int sk2 = (lane & 1) ? S.w : S.z;
    sk = (lane & 2) ? sk2 : sk;
    *a_out = as1[max(sk, 0) * 4 + head];
    return sk;
  };
  auto mkP = [&](int sk, float a) {
    float pk = (sk >= 0) ? __expf(leaky(a + ad)) : 0.f;
    return make_float4(__shfl(pk, pbase), __shfl(pk, pbase + 1),
                       __shfl(pk, pbase + 2), __shfl(pk, pbase + 3));
  };
  auto gat = [&](int s) {
    return *reinterpret_cast<const uint2*>(
        &h1[(size_t)max(s, 0) * 256 + lane * 4]);
  };

  float l = 0.f, a0 = 0.f, a1 = 0.f, a2 = 0.f, a3 = 0.f;

  int4 Sg0 = ldS(0), Sg1 = ldS(1);
  int4 SgP = ldS(2);
  uint2 HA0 = gat(Sg0.x), HA1 = gat(Sg0.y), HA2 = gat(Sg0.z), HA3 = gat(Sg0.w);
  uint2 HB0 = gat(Sg1.x), HB1 = gat(Sg1.y), HB2 = gat(Sg1.z), HB3 = gat(Sg1.w);
  float aKA, aKB;
  int skA = gK(Sg0, &aKA);
  int skB = gK(Sg1, &aKB);
  float4 PA = mkP(skA, aKA), PB;

  int j = 0;
  auto step = [&](float4& Pc, float4& Pn, uint2& Hc0, uint2& Hc1, uint2& Hc2,
                  uint2& Hc3, int& skN, float& aKN, int skC, float aKC) {
    Pn = mkP(skC, aKC);
    skN = gK(SgP, &aKN);
    l += Pc.x + Pc.y + Pc.z + Pc.w;
    a0 += Pc.x * lof(Hc0.x) + Pc.y * lof(Hc1.x) + Pc.z * lof(Hc2.x) +
          Pc.w * lof(Hc3.x);
    a1 += Pc.x * hif(Hc0.x) + Pc.y * hif(Hc1.x) + Pc.z * hif(Hc2.x) +
          Pc.w * hif(Hc3.x);
    a2 += Pc.x * lof(Hc0.y) + Pc.y * lof(Hc1.y) + Pc.z * lof(Hc2.y) +
          Pc.w * lof(Hc3.y);
    a3 += Pc.x * hif(Hc0.y) + Pc.y * hif(Hc1.y) + Pc.z * hif(Hc2.y) +
          Pc.w * hif(Hc3.y);
    Hc0 = gat(SgP.x); Hc1 = gat(SgP.y); Hc2 = gat(SgP.z); Hc3 = gat(SgP.w);
    SgP = ldS(j + 3);
  };

  for (;;) {
    step(PA, PB, HA0, HA1, HA2, HA3, skA, aKA, skB, aKB);
    if (++j > last) break;
    step(PB, PA, HB0, HB1, HB2, HB3, skB, aKB, skA, aKA);
    if (++j > last) break;
  }

  float inv = 1.0f / l;
  int col = lane * 4;
  float4 b4 = *reinterpret_cast<const float4*>(&bias[col]);
  float o0 = a0 * inv + b4.x;
  float o1 = a1 * inv + b4.y;
  float o2 = a2 * inv + b4.z;
  float o3 = a3 * inv + b4.w;
  o0 = o0 > 0.f ? o0 : __expf(o0) - 1.f;
  o1 = o1 > 0.f ? o1 : __expf(o1) - 1.f;
  o2 = o2 > 0.f ? o2 : __expf(o2) - 1.f;
  o3 = o3 > 0.f ? o3 : __expf(o3) - 1.f;
  unsigned short q[4];
  q[0] = f_to_bf16u(o0); q[1] = f_to_bf16u(o1);
  q[2] = f_to_bf16u(o2); q[3] = f_to_bf16u(o3);
  *reinterpret_cast<ushort4*>(&out[(size_t)wave * 256 + col]) =
      *reinterpret_cast<const ushort4*>(q);
}

// ---------------------------------------------------------------------------
// Layer-2 aggregation: same 2-phase structure, lane = channel.
// ---------------------------------------------------------------------------
__global__ __launch_bounds__(256) void agg2_kernel(
    const unsigned short* __restrict__ h2, const float* __restrict__ as2,
    const float* __restrict__ ad2, const int* __restrict__ ssrc,
    const int* __restrict__ offsets, const int* __restrict__ deg,
    const float* __restrict__ bias, float* __restrict__ out, int n_nodes) {
  int wave = (int)((blockIdx.x * blockDim.x + threadIdx.x) >> 6);
  int lane = threadIdx.x & 63;
  if (wave >= n_nodes) return;
  int off = offsets[wave];
  int cnt = deg[wave];
  int last = ((cnt + 3) >> 2) - 1;
  const int* S_ = ssrc + off;
  float ad = ad2[wave];

  auto ldS = [&](int g) {
    return *reinterpret_cast<const int4*>(S_ + min(g, last) * 4);
  };
  auto gK = [&](int4 S, float* a_out) {
    int sk = (lane & 1) ? S.y : S.x;
    int sk2 = (lane & 1) ? S.w : S.z;
    sk = (lane & 2) ? sk2 : sk;
    *a_out = as2[max(sk, 0)];
    return sk;
  };
  auto mkP = [&](int sk, float a) {
    float pk = (sk >= 0) ? __expf(leaky(a + ad)) : 0.f;
    return make_float4(__shfl(pk, 0), __shfl(pk, 1), __shfl(pk, 2),
                       __shfl(pk, 3));
  };
  auto gat = [&](int s) { return h2[(size_t)max(s, 0) * 64 + lane]; };

  float l = 0.f, acc = 0.f;

  int4 Sg0 = ldS(0), Sg1 = ldS(1);
  int4 SgP = ldS(2);
  unsigned short HA0 = gat(Sg0.x), HA1 = gat(Sg0.y), HA2 = gat(Sg0.z),
                 HA3 = gat(Sg0.w);
  unsigned short HB0 = gat(Sg1.x), HB1 = gat(Sg1.y), HB2 = gat(Sg1.z),
                 HB3 = gat(Sg1.w);
  float aKA, aKB;
  int skA = gK(Sg0, &aKA);
  int skB = gK(Sg1, &aKB);
  float4 PA = mkP(skA, aKA), PB;

  int j = 0;
  auto step = [&](float4& Pc, float4& Pn, unsigned short& Hc0,
                  unsigned short& Hc1, unsigned short& Hc2, unsigned short& Hc3,
                  int& skN, float& aKN, int skC, float aKC) {
    Pn = mkP(skC, aKC);
    skN = gK(SgP, &aKN);
    l += Pc.x + Pc.y + Pc.z + Pc.w;
    acc += Pc.x * bf16u_to_f(Hc0) + Pc.y * bf16u_to_f(Hc1) +
           Pc.z * bf16u_to_f(Hc2) + Pc.w * bf16u_to_f(Hc3);
    Hc0 = gat(SgP.x); Hc1 = gat(SgP.y); Hc2 = gat(SgP.z); Hc3 = gat(SgP.w);
    SgP = ldS(j + 3);
  };

  for (;;) {
    step(PA, PB, HA0, HA1, HA2, HA3, skA, aKA, skB, aKB);
    if (++j > last) break;
    step(PB, PA, HB0, HB1, HB2, HB3, skB, aKB, skA, aKA);
    if (++j > last) break;
  }

  out[(size_t)wave * 64 + lane] = acc / l + bias[lane];
}

// ---------------------------------------------------------------------------
extern "C" void kernel_launch(void* const* d_in, const int* in_sizes, int n_in,
                              void* d_out, int out_size, void* d_ws,
                              size_t ws_size, hipStream_t stream) {
  const float* x = (const float*)d_in[0];
  const int* edge_index = (const int*)d_in[1];
  const float* W1 = (const float*)d_in[2];
  const float* att_src1 = (const float*)d_in[3];
  const float* att_dst1 = (const float*)d_in[4];
  const float* b1 = (const float*)d_in[5];
  const float* W2 = (const float*)d_in[6];
  const float* att_src2 = (const float*)d_in[7];
  const float* att_dst2 = (const float*)d_in[8];
  const float* b2 = (const float*)d_in[9];

  const int n = in_sizes[0] / IN_C;  // 50000
  const int E = in_sizes[1] / 2;     // 850000
  const int* src = edge_index;
  const int* dst = edge_index + E;
  const int nb = (n + 255) / 256;
  const int stride = (E + 4 * n + 3) & ~3;

  char* ws = (char*)d_ws;
  size_t off = 0;
  auto carve = [&](size_t bytes) -> void* {
    void* p = ws + off;
    off = (off + bytes + 255) & ~(size_t)255;
    return p;
  };
  unsigned short* h1b = (unsigned short*)carve((size_t)n * 256 * 2);
  unsigned short* hact = (unsigned short*)carve((size_t)n * 256 * 2);
  unsigned short* h2b = (unsigned short*)carve((size_t)n * 64 * 2);
  unsigned short* B1img = (unsigned short*)carve(32768 * 2);
  unsigned short* B2img = (unsigned short*)carve(16384 * 2);
  float* as1 = (float*)carve((size_t)n * 4 * 4);
  float* ad1 = (float*)carve((size_t)n * 4 * 4);
  float* as2 = (float*)carve((size_t)n * 4);
  float* ad2 = (float*)carve((size_t)n * 4);
  int* deg = (int*)carve((size_t)n * 4);
  int* offsets = (int*)carve((size_t)n * 4);
  int* rank = (int*)carve((size_t)E * 4);
  int* ssrc = (int*)carve((size_t)stride * 4);
  int* partials = (int*)carve((size_t)nb * 4);

  // Setup: W images + deg zeroing (one dispatch).
  {
    int zb = (n + 1023) / 1024;
    setup_kernel<<<24 + zb, 256, 0, stream>>>(W1, W2, B1img, B2img, deg, n);
  }
  // GEMM1 + attn1 fused, concurrent with hist_rank.
  {
    int G1 = (n + 63) / 64;
    int H = (E + 1023) / 1024;
    gemm1_hist_kernel<<<G1 + H, 256, 0, stream>>>(
        x, B1img, att_src1, att_dst1, h1b, as1, ad1, n, G1, dst, E, deg, rank);
  }
  scan_partial_kernel<<<nb, 256, 0, stream>>>(deg, n, partials);
  scan_expand_kernel<<<nb, 256, 0, stream>>>(deg, n, partials, nb, offsets,
                                             ssrc);
  scatter_kernel<<<(E / 4 + 255) / 256, 256, 0, stream>>>(src, dst, rank,
                                                          offsets, E, ssrc);
  agg1_kernel<<<(n * 64 + 255) / 256, 256, 0, stream>>>(
      h1b, as1, ad1, ssrc, offsets, deg, b1, hact, n);
  mfma_gemm2<<<(n + 63) / 64, 256, 0, stream>>>(hact, B2img, att_src2,
                                                att_dst2, h2b, as2, ad2, n);
  agg2_kernel<<<(n * 64 + 255) / 256, 256, 0, stream>>>(
      h2b, as2, ad2, ssrc, offsets, deg, b2, (float*)d_out, n);
}